// Round 4
// baseline (563.075 us; speedup 1.0000x reference)
//
#include <hip/hip_runtime.h>

#define CDIM 512
#define TDIM 2048
#define KCODE 1024
#define NTOT 16
#define FH_ELEMS (NTOT * CDIM * TDIM)   // 16777216
#define M_TOTAL 61440                   // 16*(2048+1024+512+256)

typedef unsigned long long u64;
typedef unsigned int u32;
typedef __attribute__((ext_vector_type(8))) short s16x8;
typedef __attribute__((ext_vector_type(4))) float f32x4;
typedef __attribute__((ext_vector_type(4))) int i32x4;

__device__ __forceinline__ u64 umin64(u64 a, u64 b) { return a < b ? a : b; }

// round-to-nearest-even fp32 -> bf16 bits
__device__ __forceinline__ u32 bf16_rne(float f) {
  u32 u = __float_as_uint(f);
  return (u + 0x7fffu + ((u >> 16) & 1u)) >> 16;
}
// pack hi/lo split: low16 = hi bf16 (k-unit 2c), high16 = lo bf16 (k-unit 2c+1)
__device__ __forceinline__ u32 split_pack(float v) {
  u32 hi = bf16_rne(v);
  float lo = v - __uint_as_float(hi << 16);
  return hi | (bf16_rne(lo) << 16);
}
// byte offset of (m_local row, kbyte) inside a 16KB tile, XOR-swizzled
__device__ __forceinline__ int tile_addr(int ml, int kbyte) {
  return (ml * 128 + kbyte) ^ ((ml & 7) << 4);
}
// row offset of scale-S index block inside packed[]
template <int S>
__device__ __forceinline__ constexpr int pack_off() {
  return S == 1 ? 0 : S == 2 ? 32768 : S == 4 ? 49152 : 57344;
}

// ---------------------------------------------------------------------------
// csq[k] = sum(codebook[k]^2)
__global__ __launch_bounds__(64) void csq_kernel(const float* __restrict__ cb,
                                                 float* __restrict__ csq) {
  const int code = blockIdx.x;
  const int t = threadIdx.x;
  const float* row = cb + (size_t)code * CDIM;
  float s = 0.f;
#pragma unroll
  for (int q = 0; q < 2; ++q) {
    float4 v = *(const float4*)(row + (t * 2 + q) * 4);
    s += v.x * v.x + v.y * v.y + v.z * v.z + v.w * v.w;
  }
#pragma unroll
  for (int off = 32; off; off >>= 1) s += __shfl_down(s, off, 64);
  if (t == 0) csq[code] = s;
}

// ---------------------------------------------------------------------------
// Pre-split codebook: tiled [code_tile 0..7][kc 0..15][16KB], XOR-swizzled.
__global__ __launch_bounds__(256) void cbprep_kernel(const float* __restrict__ cb,
                                                     char* __restrict__ cb_pack) {
  const int g = blockIdx.x * 256 + threadIdx.x;  // 131072 threads x 16B = 2MB
  const int tile = g >> 10;
  const int L = (g & 1023) * 16;
  const int nt = tile >> 4, kc = tile & 15;
  const int code_local = L >> 7;
  const int kbyte = (L & 127) ^ ((code_local & 7) << 4);
  const int c_rel0 = kbyte >> 2;
  const int code = nt * 128 + code_local;
  const int c0 = kc * 32 + c_rel0;
  f32x4 v = *(const f32x4*)(cb + (size_t)code * CDIM + c0);
  i32x4 o;
#pragma unroll
  for (int j = 0; j < 4; ++j) o[j] = (int)split_pack(v[j]);
  *(i32x4*)(cb_pack + (size_t)g * 16) = o;
}

// ---------------------------------------------------------------------------
// A1 = packed split of x, tiled [m_tile][kc][16KB] swizzled. Thread: 4c x 4t.
__global__ __launch_bounds__(256) void xprep_kernel(const float* __restrict__ x,
                                                    char* __restrict__ a1) {
  const int tid = threadIdx.x, w = tid >> 6, lane = tid & 63;
  const int task = blockIdx.x * 4 + w;  // [n:16][cg:128][tw:8]
  const int tw = task & 7;
  const int cg = (task >> 3) & 127;
  const int n = task >> 10;
  const int c0 = cg * 4;
  const int t0 = tw * 256 + lane * 4;
  const size_t base = (size_t)n * (CDIM * TDIM) + (size_t)c0 * TDIM + t0;
  u32 pk[4][4];  // [c][t]
#pragma unroll
  for (int j = 0; j < 4; ++j) {
    f32x4 v = *(const f32x4*)(x + base + j * TDIM);
#pragma unroll
    for (int tt = 0; tt < 4; ++tt) pk[j][tt] = split_pack(v[tt]);
  }
  const int kc = c0 >> 5, kbyte = (c0 & 31) * 4;
#pragma unroll
  for (int tt = 0; tt < 4; ++tt) {
    const int m = n * TDIM + t0 + tt;
    i32x4 o = {(int)pk[0][tt], (int)pk[1][tt], (int)pk[2][tt], (int)pk[3][tt]};
    *(i32x4*)(a1 + (((size_t)((m >> 7) * 16 + kc)) << 14) +
              tile_addr(m & 127, kbyte)) = o;
  }
}

// ---------------------------------------------------------------------------
// Scale-independent MFMA distance GEMM + argmin; both operands pre-packed.
__global__ __launch_bounds__(256, 4) void gemm_argmin_packed(
    const char* __restrict__ a_pack,   // [m_tiles][16][16KB]
    const char* __restrict__ cb_pack,  // [8][16][16KB]
    const float* __restrict__ csq,
    u64* __restrict__ packed) {
  __shared__ __align__(16) char smem[16384 * 2 + 512];
  char* xs = smem;
  char* cbs = smem + 16384;
  float* csq_s = (float*)(smem + 32768);

  const int tid = threadIdx.x;
  const int lane = tid & 63;
  const int w = tid >> 6;
  const int row_base = blockIdx.x * 128;
  const int code_base = blockIdx.y * 128;
  if (tid < 128) csq_s[tid] = csq[code_base + tid];

  const f32x4 zero = {0.f, 0.f, 0.f, 0.f};
  f32x4 acc[4][4];
#pragma unroll
  for (int fc = 0; fc < 4; ++fc)
#pragma unroll
    for (int fm = 0; fm < 4; ++fm) acc[fc][fm] = zero;

  const size_t a0 = ((size_t)blockIdx.x * 16) << 14;
  const size_t b0 = ((size_t)blockIdx.y * 16) << 14;
  const int wc = w >> 1, wm = w & 1;

  for (int kc = 0; kc < 16; ++kc) {
    __syncthreads();
    const char* gA = a_pack + a0 + ((size_t)kc << 14);
    const char* gB = cb_pack + b0 + ((size_t)kc << 14);
    char* la = xs + (w << 10);
    char* lb = cbs + (w << 10);
#pragma unroll
    for (int p = 0; p < 4; ++p) {
      __builtin_amdgcn_global_load_lds(
          (const __attribute__((address_space(1))) u32*)(gA + (p << 12) + (tid << 4)),
          (__attribute__((address_space(3))) u32*)(la + (p << 12)), 16, 0, 0);
      __builtin_amdgcn_global_load_lds(
          (const __attribute__((address_space(1))) u32*)(gB + (p << 12) + (tid << 4)),
          (__attribute__((address_space(3))) u32*)(lb + (p << 12)), 16, 0, 0);
    }
    __syncthreads();
#pragma unroll
    for (int ks = 0; ks < 2; ++ks) {
      s16x8 af[4], bq[4];
#pragma unroll
      for (int fc = 0; fc < 4; ++fc) {
        const int row = wc * 64 + fc * 16 + (lane & 15);
        af[fc] = *(const s16x8*)(cbs + tile_addr(row, ks * 64 + (lane >> 4) * 16));
      }
#pragma unroll
      for (int fm = 0; fm < 4; ++fm) {
        const int row = wm * 64 + fm * 16 + (lane & 15);
        bq[fm] = *(const s16x8*)(xs + tile_addr(row, ks * 64 + (lane >> 4) * 16));
      }
#pragma unroll
      for (int fc = 0; fc < 4; ++fc)
#pragma unroll
        for (int fm = 0; fm < 4; ++fm)
          acc[fc][fm] = __builtin_amdgcn_mfma_f32_16x16x32_bf16(
              af[fc], bq[fm], acc[fc][fm], 0, 0, 0);
    }
  }

  u64 best[4] = {~0ull, ~0ull, ~0ull, ~0ull};
#pragma unroll
  for (int fc = 0; fc < 4; ++fc) {
#pragma unroll
    for (int r = 0; r < 4; ++r) {
      const int cl = wc * 64 + fc * 16 + (lane >> 4) * 4 + r;
      const float cs = csq_s[cl];
      const u64 codebits = (u32)(code_base + cl);
#pragma unroll
      for (int fm = 0; fm < 4; ++fm) {
        float d = fmaf(-2.0f, acc[fc][fm][r], cs);
        u32 u = __float_as_uint(d);
        u = (u & 0x80000000u) ? ~u : (u | 0x80000000u);
        best[fm] = umin64(best[fm], ((u64)u << 32) | codebits);
      }
    }
  }
#pragma unroll
  for (int fm = 0; fm < 4; ++fm) {
    u64 b = best[fm];
#pragma unroll
    for (int off = 16; off < 64; off <<= 1) {
      u32 lo = (u32)b, hi = (u32)(b >> 32);
      lo = (u32)__shfl_xor((int)lo, off, 64);
      hi = (u32)__shfl_xor((int)hi, off, 64);
      b = umin64(b, ((u64)hi << 32) | lo);
    }
    if ((lane >> 4) == 0)
      atomicMin(&packed[row_base + wm * 64 + fm * 16 + (lane & 15)], b);
  }
}

// ---------------------------------------------------------------------------
// subtract upsampled scale-S reconstruction from r (4 channels x 4 t)
template <int S>
__device__ __forceinline__ void subtract_scale(f32x4 r[4],
                                               const float* __restrict__ cb,
                                               const u64* __restrict__ packed,
                                               int n, int t0, int c0) {
  constexpr int t_s = TDIM / S;
  const u64* idxp = packed + pack_off<S>() + n * t_s;
#pragma unroll
  for (int tt = 0; tt < 4; ++tt) {
    const int t = t0 + tt;
    f32x4 upt;
    if constexpr (S == 1) {
      const int i0 = (int)(idxp[t] & 0xffffffffull);
      upt = *(const f32x4*)(cb + (size_t)i0 * CDIM + c0);
    } else {
      float pos = fminf(fmaxf((t + 0.5f) * (1.0f / (float)S) - 0.5f, 0.0f),
                        (float)(t_s - 1));
      const int lo = (int)pos;
      const int hi = min(lo + 1, t_s - 1);
      const float wgt = pos - (float)lo;
      const int i0 = (int)(idxp[lo] & 0xffffffffull);
      const int i1 = (int)(idxp[hi] & 0xffffffffull);
      f32x4 a = *(const f32x4*)(cb + (size_t)i0 * CDIM + c0);
      f32x4 b = *(const f32x4*)(cb + (size_t)i1 * CDIM + c0);
      upt = a * (1.0f - wgt) + b * wgt;
    }
#pragma unroll
    for (int j = 0; j < 4; ++j) r[j][tt] -= upt[j];
  }
}

// ---------------------------------------------------------------------------
// Re-derive r = x - sum(upsamples of scales <= SMAX) from x (no stored resid).
// Writes: loss partial; next-scale pack (PACK); f_hat = x - r (LAST).
// Thread: 4 consecutive channels x 4 consecutive t.
template <int SMAX, bool LAST, bool PACK>
__global__ __launch_bounds__(256) void upd_kernel(
    const float* __restrict__ x, float* __restrict__ fhat,
    const float* __restrict__ cb, const u64* __restrict__ packed,
    float* __restrict__ lossPart, char* __restrict__ a_next) {
  constexpr int SN = 2 * SMAX;    // next-scale pool factor
  constexpr int t_n = TDIM / SN;  // rows per n in A_next
  const int tid = threadIdx.x, w = tid >> 6, lane = tid & 63;
  const int task = blockIdx.x * 4 + w;  // [n:16][cg:128][tw:8]
  const int tw = task & 7;
  const int cg = (task >> 3) & 127;
  const int n = task >> 10;
  const int c0 = cg * 4;
  const int t0 = tw * 256 + lane * 4;
  const size_t base = (size_t)n * (CDIM * TDIM) + (size_t)c0 * TDIM + t0;

  f32x4 r[4];  // [channel] x 4t
  f32x4 xv[4];
#pragma unroll
  for (int j = 0; j < 4; ++j) {
    xv[j] = *(const f32x4*)(x + base + j * TDIM);
    r[j] = xv[j];
  }

  subtract_scale<1>(r, cb, packed, n, t0, c0);
  if constexpr (SMAX >= 2) subtract_scale<2>(r, cb, packed, n, t0, c0);
  if constexpr (SMAX >= 4) subtract_scale<4>(r, cb, packed, n, t0, c0);
  if constexpr (SMAX >= 8) subtract_scale<8>(r, cb, packed, n, t0, c0);

  float ss = 0.f;
#pragma unroll
  for (int j = 0; j < 4; ++j)
#pragma unroll
    for (int tt = 0; tt < 4; ++tt) ss += r[j][tt] * r[j][tt];

  if constexpr (LAST) {
#pragma unroll
    for (int j = 0; j < 4; ++j)
      *(f32x4*)(fhat + base + j * TDIM) = xv[j] - r[j];  // f_hat
  }

  if constexpr (PACK) {
    const int kc = c0 >> 5, kbyte = (c0 & 31) * 4;
    if constexpr (SN == 2) {
#pragma unroll
      for (int q = 0; q < 2; ++q) {
        const int m = n * t_n + (t0 >> 1) + q;
        i32x4 o;
#pragma unroll
        for (int j = 0; j < 4; ++j)
          o[j] = (int)split_pack((r[j][q * 2] + r[j][q * 2 + 1]) * 0.5f);
        *(i32x4*)(a_next + (((size_t)((m >> 7) * 16 + kc)) << 14) +
                  tile_addr(m & 127, kbyte)) = o;
      }
    } else if constexpr (SN == 4) {
      const int m = n * t_n + (t0 >> 2);
      i32x4 o;
#pragma unroll
      for (int j = 0; j < 4; ++j)
        o[j] = (int)split_pack((r[j][0] + r[j][1] + r[j][2] + r[j][3]) * 0.25f);
      *(i32x4*)(a_next + (((size_t)((m >> 7) * 16 + kc)) << 14) +
                tile_addr(m & 127, kbyte)) = o;
    } else {  // SN == 8: pair lanes (t0 ^ 4)
      float s4[4];
#pragma unroll
      for (int j = 0; j < 4; ++j) s4[j] = r[j][0] + r[j][1] + r[j][2] + r[j][3];
      i32x4 o;
#pragma unroll
      for (int j = 0; j < 4; ++j) {
        float p = __shfl_xor(s4[j], 1, 64);
        o[j] = (int)split_pack((s4[j] + p) * 0.125f);
      }
      if ((lane & 1) == 0) {
        const int m = n * t_n + (t0 >> 3);
        *(i32x4*)(a_next + (((size_t)((m >> 7) * 16 + kc)) << 14) +
                  tile_addr(m & 127, kbyte)) = o;
      }
    }
  }

  __shared__ float red[4];
#pragma unroll
  for (int off = 32; off; off >>= 1) ss += __shfl_down(ss, off, 64);
  if (lane == 0) red[w] = ss;
  __syncthreads();
  if (tid == 0) lossPart[blockIdx.x] = red[0] + red[1] + red[2] + red[3];
}

// ---------------------------------------------------------------------------
__global__ __launch_bounds__(256) void hist_kernel(const u64* __restrict__ packed,
                                                   int* __restrict__ hist) {
  const int i = blockIdx.x * 256 + threadIdx.x;  // 61440 total
  const int code = (int)(packed[i] & 0xFFFFFFFFull);
  atomicAdd(&hist[code], 1);
}

__global__ __launch_bounds__(256) void finalize_kernel(
    const float* __restrict__ lossPart, const int* __restrict__ hist,
    float* __restrict__ outTail) {
  __shared__ float red[4];
  const int tid = threadIdx.x;
  float s = 0.f;
  for (int i = tid; i < 4 * 4096; i += 256) s += lossPart[i];
#pragma unroll
  for (int off = 32; off; off >>= 1) s += __shfl_down(s, off, 64);
  if ((tid & 63) == 0) red[tid >> 6] = s;
  __syncthreads();
  const float loss =
      (red[0] + red[1] + red[2] + red[3]) * (1.0f / (4.0f * 16777216.0f));
  __syncthreads();
  float e = 0.f;
  for (int k = tid; k < KCODE; k += 256) {
    float p = (float)hist[k] * (1.0f / 61440.0f);
    e += p * logf(p + 1e-7f);
  }
#pragma unroll
  for (int off = 32; off; off >>= 1) e += __shfl_down(e, off, 64);
  if ((tid & 63) == 0) red[tid >> 6] = e;
  __syncthreads();
  if (tid == 0) {
    outTail[0] = loss;
    outTail[1] = expf(-(red[0] + red[1] + red[2] + red[3]));
  }
}

// ---------------------------------------------------------------------------
extern "C" void kernel_launch(void* const* d_in, const int* in_sizes, int n_in,
                              void* d_out, int out_size, void* d_ws,
                              size_t ws_size, hipStream_t stream) {
  const float* x = (const float*)d_in[0];
  const float* cb = (const float*)d_in[1];
  float* out = (float*)d_out;

  char* ws = (char*)d_ws;
  u64* packed = (u64*)ws;                   // 491520 B
  float* csq = (float*)(ws + 491520);       // 4096 B
  int* hist = (int*)(ws + 495616);          // 4096 B
  float* lossPart = (float*)(ws + 499712);  // 65536 B (4 x 4096)
  char* cb_pack = ws + 565248;              // 2 MiB
  char* a2 = ws + (4ull << 20);             // 32 MiB
  char* a4 = ws + (36ull << 20);            // 16 MiB
  char* a8 = ws + (52ull << 20);            // 8 MiB

  hipMemsetAsync(packed, 0xFF, (size_t)M_TOTAL * 8, stream);
  hipMemsetAsync(hist, 0, KCODE * sizeof(int), stream);
  csq_kernel<<<KCODE, 64, 0, stream>>>(cb, csq);
  cbprep_kernel<<<512, 256, 0, stream>>>(cb, cb_pack);

  u64* p1 = packed;          // 32768 rows (t_s=2048)
  u64* p2 = packed + 32768;  // 16384 rows
  u64* p4 = packed + 49152;  //  8192 rows
  u64* p8 = packed + 57344;  //  4096 rows

  char* a1 = (char*)out;  // A1 pack lives in d_out until upd<8> writes f_hat
  xprep_kernel<<<4096, 256, 0, stream>>>(x, a1);
  gemm_argmin_packed<<<dim3(256, 8), 256, 0, stream>>>(a1, cb_pack, csq, p1);
  upd_kernel<1, false, true>
      <<<4096, 256, 0, stream>>>(x, nullptr, cb, packed, lossPart, a2);
  gemm_argmin_packed<<<dim3(128, 8), 256, 0, stream>>>(a2, cb_pack, csq, p2);
  upd_kernel<2, false, true>
      <<<4096, 256, 0, stream>>>(x, nullptr, cb, packed, lossPart + 4096, a4);
  gemm_argmin_packed<<<dim3(64, 8), 256, 0, stream>>>(a4, cb_pack, csq, p4);
  upd_kernel<4, false, true>
      <<<4096, 256, 0, stream>>>(x, nullptr, cb, packed, lossPart + 8192, a8);
  gemm_argmin_packed<<<dim3(32, 8), 256, 0, stream>>>(a8, cb_pack, csq, p8);
  upd_kernel<8, true, false>
      <<<4096, 256, 0, stream>>>(x, out, cb, packed, lossPart + 12288, nullptr);

  hist_kernel<<<240, 256, 0, stream>>>(packed, hist);
  finalize_kernel<<<1, 256, 0, stream>>>(lossPart, hist, out + FH_ELEMS);
}

// Round 5
// 384.083 us; speedup vs baseline: 1.4660x; 1.4660x over previous
//
#include <hip/hip_runtime.h>

#define CDIM 512
#define TDIM 2048
#define KCODE 1024
#define NTOT 16
#define FH_ELEMS (NTOT * CDIM * TDIM)   // 16777216
#define M_TOTAL 61440                   // 16*(2048+1024+512+256)

typedef unsigned long long u64;
typedef unsigned int u32;
typedef __attribute__((ext_vector_type(8))) short s16x8;
typedef __attribute__((ext_vector_type(4))) float f32x4;
typedef __attribute__((ext_vector_type(4))) int i32x4;

__device__ __forceinline__ u64 umin64(u64 a, u64 b) { return a < b ? a : b; }

// round-to-nearest-even fp32 -> bf16 bits
__device__ __forceinline__ u32 bf16_rne(float f) {
  u32 u = __float_as_uint(f);
  return (u + 0x7fffu + ((u >> 16) & 1u)) >> 16;
}
// pack hi/lo split: low16 = hi bf16 (k-unit 2c), high16 = lo bf16 (k-unit 2c+1)
__device__ __forceinline__ u32 split_pack(float v) {
  u32 hi = bf16_rne(v);
  float lo = v - __uint_as_float(hi << 16);
  return hi | (bf16_rne(lo) << 16);
}
// byte offset of (m_local row, kbyte) inside a 16KB tile, XOR-swizzled
__device__ __forceinline__ int tile_addr(int ml, int kbyte) {
  return (ml * 128 + kbyte) ^ ((ml & 7) << 4);
}
__device__ __forceinline__ int iclamp(int v, int lo, int hi) {
  return v < lo ? lo : (v > hi ? hi : v);
}

// ---------------------------------------------------------------------------
// csq[k] = sum(codebook[k]^2)
__global__ __launch_bounds__(64) void csq_kernel(const float* __restrict__ cb,
                                                 float* __restrict__ csq) {
  const int code = blockIdx.x;
  const int t = threadIdx.x;
  const float* row = cb + (size_t)code * CDIM;
  float s = 0.f;
#pragma unroll
  for (int q = 0; q < 2; ++q) {
    float4 v = *(const float4*)(row + (t * 2 + q) * 4);
    s += v.x * v.x + v.y * v.y + v.z * v.z + v.w * v.w;
  }
#pragma unroll
  for (int off = 32; off; off >>= 1) s += __shfl_down(s, off, 64);
  if (t == 0) csq[code] = s;
}

// ---------------------------------------------------------------------------
// Pre-split codebook: tiled [code_tile 0..7][kc 0..15][16KB], XOR-swizzled.
__global__ __launch_bounds__(256) void cbprep_kernel(const float* __restrict__ cb,
                                                     char* __restrict__ cb_pack) {
  const int g = blockIdx.x * 256 + threadIdx.x;  // 131072 threads x 16B = 2MB
  const int tile = g >> 10;
  const int L = (g & 1023) * 16;
  const int nt = tile >> 4, kc = tile & 15;
  const int code_local = L >> 7;
  const int kbyte = (L & 127) ^ ((code_local & 7) << 4);
  const int c_rel0 = kbyte >> 2;
  const int code = nt * 128 + code_local;
  const int c0 = kc * 32 + c_rel0;
  f32x4 v = *(const f32x4*)(cb + (size_t)code * CDIM + c0);
  i32x4 o;
#pragma unroll
  for (int j = 0; j < 4; ++j) o[j] = (int)split_pack(v[j]);
  *(i32x4*)(cb_pack + (size_t)g * 16) = o;
}

// ---------------------------------------------------------------------------
// A1 = packed split of x, tiled [m_tile][kc][16KB] swizzled. Thread: 4c x 4t.
__global__ __launch_bounds__(256) void xprep_kernel(const float* __restrict__ x,
                                                    char* __restrict__ a1) {
  const int tid = threadIdx.x, w = tid >> 6, lane = tid & 63;
  const int task = blockIdx.x * 4 + w;  // [n:16][cg:128][tw:8]
  const int tw = task & 7;
  const int cg = (task >> 3) & 127;
  const int n = task >> 10;
  const int c0 = cg * 4;
  const int t0 = tw * 256 + lane * 4;
  const size_t base = (size_t)n * (CDIM * TDIM) + (size_t)c0 * TDIM + t0;
  u32 pk[4][4];  // [c][t]
#pragma unroll
  for (int j = 0; j < 4; ++j) {
    f32x4 v = *(const f32x4*)(x + base + j * TDIM);
#pragma unroll
    for (int tt = 0; tt < 4; ++tt) pk[j][tt] = split_pack(v[tt]);
  }
  const int kc = c0 >> 5, kbyte = (c0 & 31) * 4;
#pragma unroll
  for (int tt = 0; tt < 4; ++tt) {
    const int m = n * TDIM + t0 + tt;
    i32x4 o = {(int)pk[0][tt], (int)pk[1][tt], (int)pk[2][tt], (int)pk[3][tt]};
    *(i32x4*)(a1 + (((size_t)((m >> 7) * 16 + kc)) << 14) +
              tile_addr(m & 127, kbyte)) = o;
  }
}

// ---------------------------------------------------------------------------
// Scale-independent MFMA distance GEMM + argmin; both operands pre-packed.
__global__ __launch_bounds__(256, 4) void gemm_argmin_packed(
    const char* __restrict__ a_pack,   // [m_tiles][16][16KB]
    const char* __restrict__ cb_pack,  // [8][16][16KB]
    const float* __restrict__ csq,
    u64* __restrict__ packed) {
  __shared__ __align__(16) char smem[16384 * 2 + 512];
  char* xs = smem;
  char* cbs = smem + 16384;
  float* csq_s = (float*)(smem + 32768);

  const int tid = threadIdx.x;
  const int lane = tid & 63;
  const int w = tid >> 6;
  const int row_base = blockIdx.x * 128;
  const int code_base = blockIdx.y * 128;
  if (tid < 128) csq_s[tid] = csq[code_base + tid];

  const f32x4 zero = {0.f, 0.f, 0.f, 0.f};
  f32x4 acc[4][4];
#pragma unroll
  for (int fc = 0; fc < 4; ++fc)
#pragma unroll
    for (int fm = 0; fm < 4; ++fm) acc[fc][fm] = zero;

  const size_t a0 = ((size_t)blockIdx.x * 16) << 14;
  const size_t b0 = ((size_t)blockIdx.y * 16) << 14;
  const int wc = w >> 1, wm = w & 1;

  for (int kc = 0; kc < 16; ++kc) {
    __syncthreads();
    const char* gA = a_pack + a0 + ((size_t)kc << 14);
    const char* gB = cb_pack + b0 + ((size_t)kc << 14);
    char* la = xs + (w << 10);
    char* lb = cbs + (w << 10);
#pragma unroll
    for (int p = 0; p < 4; ++p) {
      __builtin_amdgcn_global_load_lds(
          (const __attribute__((address_space(1))) u32*)(gA + (p << 12) + (tid << 4)),
          (__attribute__((address_space(3))) u32*)(la + (p << 12)), 16, 0, 0);
      __builtin_amdgcn_global_load_lds(
          (const __attribute__((address_space(1))) u32*)(gB + (p << 12) + (tid << 4)),
          (__attribute__((address_space(3))) u32*)(lb + (p << 12)), 16, 0, 0);
    }
    __syncthreads();
#pragma unroll
    for (int ks = 0; ks < 2; ++ks) {
      s16x8 af[4], bq[4];
#pragma unroll
      for (int fc = 0; fc < 4; ++fc) {
        const int row = wc * 64 + fc * 16 + (lane & 15);
        af[fc] = *(const s16x8*)(cbs + tile_addr(row, ks * 64 + (lane >> 4) * 16));
      }
#pragma unroll
      for (int fm = 0; fm < 4; ++fm) {
        const int row = wm * 64 + fm * 16 + (lane & 15);
        bq[fm] = *(const s16x8*)(xs + tile_addr(row, ks * 64 + (lane >> 4) * 16));
      }
#pragma unroll
      for (int fc = 0; fc < 4; ++fc)
#pragma unroll
        for (int fm = 0; fm < 4; ++fm)
          acc[fc][fm] = __builtin_amdgcn_mfma_f32_16x16x32_bf16(
              af[fc], bq[fm], acc[fc][fm], 0, 0, 0);
    }
  }

  u64 best[4] = {~0ull, ~0ull, ~0ull, ~0ull};
#pragma unroll
  for (int fc = 0; fc < 4; ++fc) {
#pragma unroll
    for (int r = 0; r < 4; ++r) {
      const int cl = wc * 64 + fc * 16 + (lane >> 4) * 4 + r;
      const float cs = csq_s[cl];
      const u64 codebits = (u32)(code_base + cl);
#pragma unroll
      for (int fm = 0; fm < 4; ++fm) {
        float d = fmaf(-2.0f, acc[fc][fm][r], cs);
        u32 u = __float_as_uint(d);
        u = (u & 0x80000000u) ? ~u : (u | 0x80000000u);
        best[fm] = umin64(best[fm], ((u64)u << 32) | codebits);
      }
    }
  }
#pragma unroll
  for (int fm = 0; fm < 4; ++fm) {
    u64 b = best[fm];
#pragma unroll
    for (int off = 16; off < 64; off <<= 1) {
      u32 lo = (u32)b, hi = (u32)(b >> 32);
      lo = (u32)__shfl_xor((int)lo, off, 64);
      hi = (u32)__shfl_xor((int)hi, off, 64);
      b = umin64(b, ((u64)hi << 32) | lo);
    }
    if ((lane >> 4) == 0)
      atomicMin(&packed[row_base + wm * 64 + fm * 16 + (lane & 15)], b);
  }
}

// ---------------------------------------------------------------------------
// pack2: A2 = pool2(x - up1) (exact FP order vs reference) + poolr2 f32.
// Block: one n, 8 coarse tau (16 full-res t). Phase A stages the 16 scale-1
// code rows coalesced (lanes along c); Phase B lanes along t.
__global__ __launch_bounds__(256) void pack2_kernel(
    const float* __restrict__ x, const float* __restrict__ cb,
    const u64* __restrict__ packed, char* __restrict__ a2,
    float* __restrict__ poolr2) {
  __shared__ float rows1[16][516];
  __shared__ int idx1[16];
  const int tid = threadIdx.x;
  const int blk = blockIdx.x;  // 16 n x 128 tiles
  const int n = blk >> 7;
  const int tau0 = (blk & 127) * 8;
  const int tb = tau0 * 2;  // full-res t in [tb, tb+16)
  if (tid < 16)
    idx1[tid] = (int)(packed[(size_t)n * TDIM + tb + tid] & 0xffffffffull);
  __syncthreads();
  {
    const int rj = tid >> 4, c16 = tid & 15;
    const float* src = cb + (size_t)idx1[rj] * CDIM;
#pragma unroll
    for (int q = 0; q < 8; ++q) {
      const int c = c16 * 4 + q * 64;
      *(f32x4*)&rows1[rj][c] = *(const f32x4*)(src + c);
    }
  }
  __syncthreads();

  const int cg = tid >> 1, half = tid & 1;
  const int c0 = cg * 4;
  const int tl0 = half * 8;  // local t base
  const size_t xbase =
      (size_t)n * (CDIM * TDIM) + (size_t)c0 * TDIM + tb + tl0;

  f32x4 ru[8];
#pragma unroll
  for (int t = 0; t < 8; ++t) ru[t] = *(const f32x4*)&rows1[tl0 + t][c0];

  float p2[4][4];  // [c][q]
#pragma unroll
  for (int j = 0; j < 4; ++j) {
    f32x4 xa = *(const f32x4*)(x + xbase + (size_t)j * TDIM);
    f32x4 xb = *(const f32x4*)(x + xbase + (size_t)j * TDIM + 4);
#pragma unroll
    for (int q = 0; q < 4; ++q) {
      const float e0 = (q < 2) ? xa[2 * q] : xb[2 * q - 4];
      const float e1 = (q < 2) ? xa[2 * q + 1] : xb[2 * q - 3];
      const float r0 = e0 - ru[2 * q][j];
      const float r1 = e1 - ru[2 * q + 1][j];
      p2[j][q] = (r0 + r1) * 0.5f;
    }
  }
  // poolr2 [n][c][1024]
#pragma unroll
  for (int j = 0; j < 4; ++j) {
    f32x4 o = {p2[j][0], p2[j][1], p2[j][2], p2[j][3]};
    *(f32x4*)(poolr2 + (size_t)n * (CDIM * 1024) + (size_t)(c0 + j) * 1024 +
              tau0 + half * 4) = o;
  }
  // a2 pack
  const int kc = c0 >> 5, kbyte = (c0 & 31) * 4;
#pragma unroll
  for (int q = 0; q < 4; ++q) {
    const int m = n * 1024 + tau0 + half * 4 + q;
    i32x4 o = {(int)split_pack(p2[0][q]), (int)split_pack(p2[1][q]),
               (int)split_pack(p2[2][q]), (int)split_pack(p2[3][q])};
    *(i32x4*)(a2 + (((size_t)((m >> 7) * 16 + kc)) << 14) +
              tile_addr(m & 127, kbyte)) = o;
  }
}

// ---------------------------------------------------------------------------
// packN: pool_{2S}(r) chain at coarse res. Input poolr_in [16][512][TP] f32
// (= pool_P(r_prev)); subtract (1/8,3/4,1/8) stencil of scale-P codes;
// pair-mean -> A_{2P} pack (+ optional poolr_out).
template <int TP, bool WPOOL>
__global__ __launch_bounds__(256) void packN_kernel(
    const float* __restrict__ pin, const float* __restrict__ cb,
    const u64* __restrict__ packed, char* __restrict__ a_next,
    float* __restrict__ pout) {
  constexpr int OFF = (TP == 1024) ? 32768 : 49152;  // scale-2 / scale-4 idx
  constexpr int TILES = TP / 16;
  constexpr int TO = TP / 2;
  __shared__ float rows[18][516];
  __shared__ int idxs[18];
  const int tid = threadIdx.x;
  const int blk = blockIdx.x;  // 16 n x TILES
  const int n = blk / TILES;
  const int o0 = (blk % TILES) * 8;  // output tau base
  const int s0 = o0 * 2;             // input sigma base
  if (tid < 18) {
    const int sig = iclamp(s0 - 1 + tid, 0, TP - 1);
    idxs[tid] = (int)(packed[OFF + (size_t)n * TP + sig] & 0xffffffffull);
  }
  __syncthreads();
  for (int j = 0; j < 18; ++j) {
    const int c = tid * 2;
    const float* src = cb + (size_t)idxs[j] * CDIM + c;
    rows[j][c] = src[0];
    rows[j][c + 1] = src[1];
  }
  __syncthreads();

  const int cg = tid >> 1, half = tid & 1;
  const int c0 = cg * 4;
  // input sigma local range [half*8, half*8+8)
  f32x4 inva[4], invb[4];
#pragma unroll
  for (int j = 0; j < 4; ++j) {
    const float* p = pin + (size_t)n * (CDIM * TP) + (size_t)(c0 + j) * TP +
                     s0 + half * 8;
    inva[j] = *(const f32x4*)p;
    invb[j] = *(const f32x4*)(p + 4);
  }

  float pv[4][4];
#pragma unroll
  for (int q = 0; q < 4; ++q) {
    const int e = half * 8 + 2 * q;  // local sigma of first of pair
    const int sa = e + 1, sb = e + 2;
    f32x4 Rm = *(const f32x4*)&rows[sa - 1][c0];
    f32x4 Rc = *(const f32x4*)&rows[sa][c0];
    f32x4 Rp = *(const f32x4*)&rows[sb][c0];
    f32x4 Rpp = *(const f32x4*)&rows[sb + 1][c0];
    f32x4 ua = 0.125f * (Rm + Rp) + 0.75f * Rc;
    f32x4 ub = 0.125f * (Rc + Rpp) + 0.75f * Rp;
#pragma unroll
    for (int j = 0; j < 4; ++j) {
      const int l = 2 * q;
      const float ia = (l < 4) ? inva[j][l] : invb[j][l - 4];
      const float ib = (l + 1 < 4) ? inva[j][l + 1] : invb[j][l - 3];
      pv[j][q] = ((ia - ua[j]) + (ib - ub[j])) * 0.5f;
    }
  }

  if constexpr (WPOOL) {
#pragma unroll
    for (int j = 0; j < 4; ++j) {
      f32x4 o = {pv[j][0], pv[j][1], pv[j][2], pv[j][3]};
      *(f32x4*)(pout + (size_t)n * (CDIM * TO) + (size_t)(c0 + j) * TO + o0 +
                half * 4) = o;
    }
  }
  const int kc = c0 >> 5, kbyte = (c0 & 31) * 4;
#pragma unroll
  for (int q = 0; q < 4; ++q) {
    const int m = n * TO + o0 + half * 4 + q;
    i32x4 o = {(int)split_pack(pv[0][q]), (int)split_pack(pv[1][q]),
               (int)split_pack(pv[2][q]), (int)split_pack(pv[3][q])};
    *(i32x4*)(a_next + (((size_t)((m >> 7) * 16 + kc)) << 14) +
              tile_addr(m & 127, kbyte)) = o;
  }
}

// ---------------------------------------------------------------------------
// final: one full-res pass: 4 per-stage losses + f_hat. Scale-1 rows LDS-
// staged (coalesced); scales 2/4/8 via per-thread row-deduped vector loads.
__global__ __launch_bounds__(256) void final_kernel(
    const float* __restrict__ x, float* __restrict__ out,
    const float* __restrict__ cb, const u64* __restrict__ packed,
    float* __restrict__ lossPart) {
  __shared__ float rows1[16][516];
  __shared__ int idx1[16];
  __shared__ float red[4][4];
  const int tid = threadIdx.x;
  const int blk = blockIdx.x;  // 16 n x 128 tiles
  const int n = blk >> 7;
  const int t0 = (blk & 127) * 16;
  if (tid < 16)
    idx1[tid] = (int)(packed[(size_t)n * TDIM + t0 + tid] & 0xffffffffull);
  __syncthreads();
  {
    const int rj = tid >> 4, c16 = tid & 15;
    const float* src = cb + (size_t)idx1[rj] * CDIM;
#pragma unroll
    for (int q = 0; q < 8; ++q) {
      const int c = c16 * 4 + q * 64;
      *(f32x4*)&rows1[rj][c] = *(const f32x4*)(src + c);
    }
  }
  __syncthreads();

  const int cg = tid >> 1, half = tid & 1;
  const int c0 = cg * 4;
  const int tb = t0 + half * 8;
  const int b2 = tb >> 1, b4 = tb >> 2, m8 = tb >> 3;
  const u64* ip2 = packed + 32768 + (size_t)n * 1024;
  const u64* ip4 = packed + 49152 + (size_t)n * 512;
  const u64* ip8 = packed + 57344 + (size_t)n * 256;

  f32x4 R2[6], R4[4], R8[3];
#pragma unroll
  for (int k = 0; k < 6; ++k) {
    const int s = iclamp(b2 - 1 + k, 0, 1023);
    R2[k] = *(const f32x4*)(
        cb + (size_t)(u32)(ip2[s] & 0xffffffffull) * CDIM + c0);
  }
#pragma unroll
  for (int k = 0; k < 4; ++k) {
    const int s = iclamp(b4 - 1 + k, 0, 511);
    R4[k] = *(const f32x4*)(
        cb + (size_t)(u32)(ip4[s] & 0xffffffffull) * CDIM + c0);
  }
#pragma unroll
  for (int k = 0; k < 3; ++k) {
    const int s = iclamp(m8 - 1 + k, 0, 255);
    R8[k] = *(const f32x4*)(
        cb + (size_t)(u32)(ip8[s] & 0xffffffffull) * CDIM + c0);
  }

  const size_t xbase = (size_t)n * (CDIM * TDIM) + (size_t)c0 * TDIM + tb;
  f32x4 xa[4], xb[4], fa[4], fb[4];
#pragma unroll
  for (int j = 0; j < 4; ++j) {
    xa[j] = *(const f32x4*)(x + xbase + (size_t)j * TDIM);
    xb[j] = *(const f32x4*)(x + xbase + (size_t)j * TDIM + 4);
  }

  // per-tt slot/weight tables (tt = t - tb)
  const int s2s[8] = {0, 1, 1, 2, 2, 3, 3, 4};
  const float w2s[8] = {0.75f, 0.25f, 0.75f, 0.25f, 0.75f, 0.25f, 0.75f, 0.25f};
  const int s4s[8] = {0, 0, 1, 1, 1, 1, 2, 2};
  const float w4s[8] = {0.625f, 0.875f, 0.125f, 0.375f,
                        0.625f, 0.875f, 0.125f, 0.375f};
  const int s8s[8] = {0, 0, 0, 0, 1, 1, 1, 1};
  const float w8s[8] = {0.5625f, 0.6875f, 0.8125f, 0.9375f,
                        0.0625f, 0.1875f, 0.3125f, 0.4375f};

  float ss1 = 0.f, ss2 = 0.f, ss3 = 0.f, ss4 = 0.f;
#pragma unroll
  for (int tt = 0; tt < 8; ++tt) {
    f32x4 ru1 = *(const f32x4*)&rows1[half * 8 + tt][c0];
    f32x4 u2 = R2[s2s[tt]] * (1.f - w2s[tt]) + R2[s2s[tt] + 1] * w2s[tt];
    f32x4 u4 = R4[s4s[tt]] * (1.f - w4s[tt]) + R4[s4s[tt] + 1] * w4s[tt];
    f32x4 u8 = R8[s8s[tt]] * (1.f - w8s[tt]) + R8[s8s[tt] + 1] * w8s[tt];
    f32x4 xv;
#pragma unroll
    for (int j = 0; j < 4; ++j) xv[j] = (tt < 4) ? xa[j][tt] : xb[j][tt - 4];
    f32x4 r1 = xv - ru1;
    f32x4 r2 = r1 - u2;
    f32x4 r3 = r2 - u4;
    f32x4 r4 = r3 - u8;
#pragma unroll
    for (int j = 0; j < 4; ++j) {
      ss1 += r1[j] * r1[j];
      ss2 += r2[j] * r2[j];
      ss3 += r3[j] * r3[j];
      ss4 += r4[j] * r4[j];
    }
    f32x4 fh = xv - r4;
#pragma unroll
    for (int j = 0; j < 4; ++j) {
      if (tt < 4)
        fa[j][tt] = fh[j];
      else
        fb[j][tt - 4] = fh[j];
    }
  }
#pragma unroll
  for (int j = 0; j < 4; ++j) {
    *(f32x4*)(out + xbase + (size_t)j * TDIM) = fa[j];
    *(f32x4*)(out + xbase + (size_t)j * TDIM + 4) = fb[j];
  }

  float sv[4] = {ss1, ss2, ss3, ss4};
  const int w = tid >> 6, lane = tid & 63;
#pragma unroll
  for (int st = 0; st < 4; ++st) {
    float v = sv[st];
#pragma unroll
    for (int off = 32; off; off >>= 1) v += __shfl_down(v, off, 64);
    if (lane == 0) red[w][st] = v;
  }
  __syncthreads();
  if (tid < 4)
    lossPart[tid * 2048 + blk] =
        red[0][tid] + red[1][tid] + red[2][tid] + red[3][tid];
}

// ---------------------------------------------------------------------------
__global__ __launch_bounds__(256) void hist_kernel(const u64* __restrict__ packed,
                                                   int* __restrict__ hist) {
  const int i = blockIdx.x * 256 + threadIdx.x;  // 61440 total
  const int code = (int)(packed[i] & 0xFFFFFFFFull);
  atomicAdd(&hist[code], 1);
}

__global__ __launch_bounds__(256) void finalize_kernel(
    const float* __restrict__ lossPart, const int* __restrict__ hist,
    float* __restrict__ outTail) {
  __shared__ float red[4];
  const int tid = threadIdx.x;
  float s = 0.f;
  for (int i = tid; i < 4 * 2048; i += 256) s += lossPart[i];
#pragma unroll
  for (int off = 32; off; off >>= 1) s += __shfl_down(s, off, 64);
  if ((tid & 63) == 0) red[tid >> 6] = s;
  __syncthreads();
  const float loss =
      (red[0] + red[1] + red[2] + red[3]) * (1.0f / (4.0f * 16777216.0f));
  __syncthreads();
  float e = 0.f;
  for (int k = tid; k < KCODE; k += 256) {
    float p = (float)hist[k] * (1.0f / 61440.0f);
    e += p * logf(p + 1e-7f);
  }
#pragma unroll
  for (int off = 32; off; off >>= 1) e += __shfl_down(e, off, 64);
  if ((tid & 63) == 0) red[tid >> 6] = e;
  __syncthreads();
  if (tid == 0) {
    outTail[0] = loss;
    outTail[1] = expf(-(red[0] + red[1] + red[2] + red[3]));
  }
}

// ---------------------------------------------------------------------------
extern "C" void kernel_launch(void* const* d_in, const int* in_sizes, int n_in,
                              void* d_out, int out_size, void* d_ws,
                              size_t ws_size, hipStream_t stream) {
  const float* x = (const float*)d_in[0];
  const float* cb = (const float*)d_in[1];
  float* out = (float*)d_out;

  char* ws = (char*)d_ws;
  u64* packed = (u64*)ws;                   // 491520 B
  float* csq = (float*)(ws + 491520);       // 4096 B
  int* hist = (int*)(ws + 495616);          // 4096 B
  float* lossPart = (float*)(ws + 499712);  // 32768 B (4 x 2048)
  char* cb_pack = ws + 565248;              // 2 MiB
  char* a2 = ws + (4ull << 20);             // 32 MiB
  char* a4 = ws + (36ull << 20);            // 16 MiB
  char* a8 = ws + (52ull << 20);            // 8 MiB

  hipMemsetAsync(packed, 0xFF, (size_t)M_TOTAL * 8, stream);
  hipMemsetAsync(hist, 0, KCODE * sizeof(int), stream);
  csq_kernel<<<KCODE, 64, 0, stream>>>(cb, csq);
  cbprep_kernel<<<512, 256, 0, stream>>>(cb, cb_pack);

  u64* p1 = packed;          // 32768 rows (t_s=2048)
  u64* p2 = packed + 32768;  // 16384 rows
  u64* p4 = packed + 49152;  //  8192 rows
  u64* p8 = packed + 57344;  //  4096 rows

  // d_out region reuse: A1 until gemm1; then poolr2 [0,32MB) + poolr4
  // [32,48MB); finally f_hat overwrites everything.
  char* a1 = (char*)out;
  float* poolr2 = out;                 // 16*512*1024 f32
  float* poolr4 = out + 8388608;       // 16*512*512 f32

  xprep_kernel<<<4096, 256, 0, stream>>>(x, a1);
  gemm_argmin_packed<<<dim3(256, 8), 256, 0, stream>>>(a1, cb_pack, csq, p1);
  pack2_kernel<<<2048, 256, 0, stream>>>(x, cb, packed, a2, poolr2);
  gemm_argmin_packed<<<dim3(128, 8), 256, 0, stream>>>(a2, cb_pack, csq, p2);
  packN_kernel<1024, true>
      <<<1024, 256, 0, stream>>>(poolr2, cb, packed, a4, poolr4);
  gemm_argmin_packed<<<dim3(64, 8), 256, 0, stream>>>(a4, cb_pack, csq, p4);
  packN_kernel<512, false>
      <<<512, 256, 0, stream>>>(poolr4, cb, packed, a8, nullptr);
  gemm_argmin_packed<<<dim3(32, 8), 256, 0, stream>>>(a8, cb_pack, csq, p8);
  final_kernel<<<2048, 256, 0, stream>>>(x, out, cb, packed, lossPart);

  hist_kernel<<<240, 256, 0, stream>>>(packed, hist);
  finalize_kernel<<<1, 256, 0, stream>>>(lossPart, hist, out + FH_ELEMS);
}

// Round 6
// 318.160 us; speedup vs baseline: 1.7698x; 1.2072x over previous
//
#include <hip/hip_runtime.h>

#define CDIM 512
#define TDIM 2048
#define KCODE 1024
#define NTOT 16
#define FH_ELEMS (NTOT * CDIM * TDIM)   // 16777216
#define M_TOTAL 61440                   // 16*(2048+1024+512+256)

typedef unsigned long long u64;
typedef unsigned int u32;
typedef __attribute__((ext_vector_type(8))) short s16x8;
typedef __attribute__((ext_vector_type(4))) float f32x4;
typedef __attribute__((ext_vector_type(4))) int i32x4;
typedef __attribute__((ext_vector_type(2))) int i32x2;

__device__ __forceinline__ u64 umin64(u64 a, u64 b) { return a < b ? a : b; }

// round-to-nearest-even fp32 -> bf16 bits
__device__ __forceinline__ u32 bf16_rne(float f) {
  u32 u = __float_as_uint(f);
  return (u + 0x7fffu + ((u >> 16) & 1u)) >> 16;
}
// pack two consecutive channels into one u32 (low16 = even channel)
__device__ __forceinline__ u32 pack2ch(float v0, float v1) {
  return bf16_rne(v0) | (bf16_rne(v1) << 16);
}
// byte offset of (m_local row, kbyte) inside a 16KB tile, XOR-swizzled
__device__ __forceinline__ int tile_addr(int ml, int kbyte) {
  return (ml * 128 + kbyte) ^ ((ml & 7) << 4);
}
__device__ __forceinline__ int iclamp(int v, int lo, int hi) {
  return v < lo ? lo : (v > hi ? hi : v);
}

// ---------------------------------------------------------------------------
// csq[k] = sum(codebook[k]^2)
__global__ __launch_bounds__(64) void csq_kernel(const float* __restrict__ cb,
                                                 float* __restrict__ csq) {
  const int code = blockIdx.x;
  const int t = threadIdx.x;
  const float* row = cb + (size_t)code * CDIM;
  float s = 0.f;
#pragma unroll
  for (int q = 0; q < 2; ++q) {
    float4 v = *(const float4*)(row + (t * 2 + q) * 4);
    s += v.x * v.x + v.y * v.y + v.z * v.z + v.w * v.w;
  }
#pragma unroll
  for (int off = 32; off; off >>= 1) s += __shfl_down(s, off, 64);
  if (t == 0) csq[code] = s;
}

// ---------------------------------------------------------------------------
// Pre-pack codebook bf16: tiled [code_tile 0..7][kc 0..7][16KB], XOR-swizzled.
// K = 512 channels (k-unit = channel).
__global__ __launch_bounds__(256) void cbprep_kernel(const float* __restrict__ cb,
                                                     char* __restrict__ cb_pack) {
  const int g = blockIdx.x * 256 + threadIdx.x;  // 65536 threads x 16B = 1MB
  const int tile = g >> 10;                      // 1024 threads per 16KB tile
  const int L = (g & 1023) * 16;
  const int nt = tile >> 3, kc = tile & 7;
  const int code_local = L >> 7;
  const int kbyte = (L & 127) ^ ((code_local & 7) << 4);
  const int code = nt * 128 + code_local;
  const int c0 = kc * 64 + (kbyte >> 1);  // 8 channels per 16B
  f32x4 va = *(const f32x4*)(cb + (size_t)code * CDIM + c0);
  f32x4 vb = *(const f32x4*)(cb + (size_t)code * CDIM + c0 + 4);
  i32x4 o = {(int)pack2ch(va[0], va[1]), (int)pack2ch(va[2], va[3]),
             (int)pack2ch(vb[0], vb[1]), (int)pack2ch(vb[2], vb[3])};
  *(i32x4*)(cb_pack + (size_t)g * 16) = o;
}

// ---------------------------------------------------------------------------
// A1 = bf16 pack of x, tiled [m_tile][kc 0..7][16KB] swizzled. Thread: 4c x 4t.
__global__ __launch_bounds__(256) void xprep_kernel(const float* __restrict__ x,
                                                    char* __restrict__ a1) {
  const int tid = threadIdx.x, w = tid >> 6, lane = tid & 63;
  const int task = blockIdx.x * 4 + w;  // [n:16][cg:128][tw:8]
  const int tw = task & 7;
  const int cg = (task >> 3) & 127;
  const int n = task >> 10;
  const int c0 = cg * 4;
  const int t0 = tw * 256 + lane * 4;
  const size_t base = (size_t)n * (CDIM * TDIM) + (size_t)c0 * TDIM + t0;
  f32x4 v[4];
#pragma unroll
  for (int j = 0; j < 4; ++j) v[j] = *(const f32x4*)(x + base + j * TDIM);
  const int kc = c0 >> 6, kbyte = (c0 & 63) * 2;
#pragma unroll
  for (int tt = 0; tt < 4; ++tt) {
    const int m = n * TDIM + t0 + tt;
    i32x2 o = {(int)pack2ch(v[0][tt], v[1][tt]),
               (int)pack2ch(v[2][tt], v[3][tt])};
    *(i32x2*)(a1 + (((size_t)((m >> 7) * 8 + kc)) << 14) +
              tile_addr(m & 127, kbyte)) = o;
  }
}

// ---------------------------------------------------------------------------
// Scale-independent MFMA distance GEMM + argmin; both operands pre-packed bf16.
__global__ __launch_bounds__(256, 4) void gemm_argmin_packed(
    const char* __restrict__ a_pack,   // [m_tiles][8][16KB]
    const char* __restrict__ cb_pack,  // [8][8][16KB]
    const float* __restrict__ csq,
    u64* __restrict__ packed) {
  __shared__ __align__(16) char smem[16384 * 2 + 512];
  char* xs = smem;
  char* cbs = smem + 16384;
  float* csq_s = (float*)(smem + 32768);

  const int tid = threadIdx.x;
  const int lane = tid & 63;
  const int w = tid >> 6;
  const int row_base = blockIdx.x * 128;
  const int code_base = blockIdx.y * 128;
  if (tid < 128) csq_s[tid] = csq[code_base + tid];

  const f32x4 zero = {0.f, 0.f, 0.f, 0.f};
  f32x4 acc[4][4];
#pragma unroll
  for (int fc = 0; fc < 4; ++fc)
#pragma unroll
    for (int fm = 0; fm < 4; ++fm) acc[fc][fm] = zero;

  const size_t a0 = ((size_t)blockIdx.x * 8) << 14;
  const size_t b0 = ((size_t)blockIdx.y * 8) << 14;
  const int wc = w >> 1, wm = w & 1;

  for (int kc = 0; kc < 8; ++kc) {
    __syncthreads();
    const char* gA = a_pack + a0 + ((size_t)kc << 14);
    const char* gB = cb_pack + b0 + ((size_t)kc << 14);
    char* la = xs + (w << 10);
    char* lb = cbs + (w << 10);
#pragma unroll
    for (int p = 0; p < 4; ++p) {
      __builtin_amdgcn_global_load_lds(
          (const __attribute__((address_space(1))) u32*)(gA + (p << 12) + (tid << 4)),
          (__attribute__((address_space(3))) u32*)(la + (p << 12)), 16, 0, 0);
      __builtin_amdgcn_global_load_lds(
          (const __attribute__((address_space(1))) u32*)(gB + (p << 12) + (tid << 4)),
          (__attribute__((address_space(3))) u32*)(lb + (p << 12)), 16, 0, 0);
    }
    __syncthreads();
#pragma unroll
    for (int ks = 0; ks < 2; ++ks) {
      s16x8 af[4], bq[4];
#pragma unroll
      for (int fc = 0; fc < 4; ++fc) {
        const int row = wc * 64 + fc * 16 + (lane & 15);
        af[fc] = *(const s16x8*)(cbs + tile_addr(row, ks * 64 + (lane >> 4) * 16));
      }
#pragma unroll
      for (int fm = 0; fm < 4; ++fm) {
        const int row = wm * 64 + fm * 16 + (lane & 15);
        bq[fm] = *(const s16x8*)(xs + tile_addr(row, ks * 64 + (lane >> 4) * 16));
      }
#pragma unroll
      for (int fc = 0; fc < 4; ++fc)
#pragma unroll
        for (int fm = 0; fm < 4; ++fm)
          acc[fc][fm] = __builtin_amdgcn_mfma_f32_16x16x32_bf16(
              af[fc], bq[fm], acc[fc][fm], 0, 0, 0);
    }
  }

  u64 best[4] = {~0ull, ~0ull, ~0ull, ~0ull};
#pragma unroll
  for (int fc = 0; fc < 4; ++fc) {
#pragma unroll
    for (int r = 0; r < 4; ++r) {
      const int cl = wc * 64 + fc * 16 + (lane >> 4) * 4 + r;
      const float cs = csq_s[cl];
      const u64 codebits = (u32)(code_base + cl);
#pragma unroll
      for (int fm = 0; fm < 4; ++fm) {
        float d = fmaf(-2.0f, acc[fc][fm][r], cs);
        u32 u = __float_as_uint(d);
        u = (u & 0x80000000u) ? ~u : (u | 0x80000000u);
        best[fm] = umin64(best[fm], ((u64)u << 32) | codebits);
      }
    }
  }
#pragma unroll
  for (int fm = 0; fm < 4; ++fm) {
    u64 b = best[fm];
#pragma unroll
    for (int off = 16; off < 64; off <<= 1) {
      u32 lo = (u32)b, hi = (u32)(b >> 32);
      lo = (u32)__shfl_xor((int)lo, off, 64);
      hi = (u32)__shfl_xor((int)hi, off, 64);
      b = umin64(b, ((u64)hi << 32) | lo);
    }
    if ((lane >> 4) == 0)
      atomicMin(&packed[row_base + wm * 64 + fm * 16 + (lane & 15)], b);
  }
}

// ---------------------------------------------------------------------------
// pack2: A2 = pool2(x - up1) + poolr2 f32. Block: one n, 8 coarse tau.
__global__ __launch_bounds__(256) void pack2_kernel(
    const float* __restrict__ x, const float* __restrict__ cb,
    const u64* __restrict__ packed, char* __restrict__ a2,
    float* __restrict__ poolr2) {
  __shared__ float rows1[16][516];
  __shared__ int idx1[16];
  const int tid = threadIdx.x;
  const int blk = blockIdx.x;  // 16 n x 128 tiles
  const int n = blk >> 7;
  const int tau0 = (blk & 127) * 8;
  const int tb = tau0 * 2;  // full-res t in [tb, tb+16)
  if (tid < 16)
    idx1[tid] = (int)(packed[(size_t)n * TDIM + tb + tid] & 0xffffffffull);
  __syncthreads();
  {
    const int rj = tid >> 4, c16 = tid & 15;
    const float* src = cb + (size_t)idx1[rj] * CDIM;
#pragma unroll
    for (int q = 0; q < 8; ++q) {
      const int c = c16 * 4 + q * 64;
      *(f32x4*)&rows1[rj][c] = *(const f32x4*)(src + c);
    }
  }
  __syncthreads();

  const int cg = tid >> 1, half = tid & 1;
  const int c0 = cg * 4;
  const int tl0 = half * 8;  // local t base
  const size_t xbase =
      (size_t)n * (CDIM * TDIM) + (size_t)c0 * TDIM + tb + tl0;

  f32x4 ru[8];
#pragma unroll
  for (int t = 0; t < 8; ++t) ru[t] = *(const f32x4*)&rows1[tl0 + t][c0];

  float p2[4][4];  // [c][q]
#pragma unroll
  for (int j = 0; j < 4; ++j) {
    f32x4 xa = *(const f32x4*)(x + xbase + (size_t)j * TDIM);
    f32x4 xb = *(const f32x4*)(x + xbase + (size_t)j * TDIM + 4);
#pragma unroll
    for (int q = 0; q < 4; ++q) {
      const float e0 = (q < 2) ? xa[2 * q] : xb[2 * q - 4];
      const float e1 = (q < 2) ? xa[2 * q + 1] : xb[2 * q - 3];
      const float r0 = e0 - ru[2 * q][j];
      const float r1 = e1 - ru[2 * q + 1][j];
      p2[j][q] = (r0 + r1) * 0.5f;
    }
  }
  // poolr2 [n][c][1024]
#pragma unroll
  for (int j = 0; j < 4; ++j) {
    f32x4 o = {p2[j][0], p2[j][1], p2[j][2], p2[j][3]};
    *(f32x4*)(poolr2 + (size_t)n * (CDIM * 1024) + (size_t)(c0 + j) * 1024 +
              tau0 + half * 4) = o;
  }
  // a2 pack
  const int kc = c0 >> 6, kbyte = (c0 & 63) * 2;
#pragma unroll
  for (int q = 0; q < 4; ++q) {
    const int m = n * 1024 + tau0 + half * 4 + q;
    i32x2 o = {(int)pack2ch(p2[0][q], p2[1][q]),
               (int)pack2ch(p2[2][q], p2[3][q])};
    *(i32x2*)(a2 + (((size_t)((m >> 7) * 8 + kc)) << 14) +
              tile_addr(m & 127, kbyte)) = o;
  }
}

// ---------------------------------------------------------------------------
// packN: pool chain at coarse res; subtract (1/8,3/4,1/8) stencil of scale-P
// codes; pair-mean -> A_{2P} pack (+ optional poolr_out).
template <int TP, bool WPOOL>
__global__ __launch_bounds__(256) void packN_kernel(
    const float* __restrict__ pin, const float* __restrict__ cb,
    const u64* __restrict__ packed, char* __restrict__ a_next,
    float* __restrict__ pout) {
  constexpr int OFF = (TP == 1024) ? 32768 : 49152;  // scale-2 / scale-4 idx
  constexpr int TILES = TP / 16;
  constexpr int TO = TP / 2;
  __shared__ float rows[18][516];
  __shared__ int idxs[18];
  const int tid = threadIdx.x;
  const int blk = blockIdx.x;  // 16 n x TILES
  const int n = blk / TILES;
  const int o0 = (blk % TILES) * 8;  // output tau base
  const int s0 = o0 * 2;             // input sigma base
  if (tid < 18) {
    const int sig = iclamp(s0 - 1 + tid, 0, TP - 1);
    idxs[tid] = (int)(packed[OFF + (size_t)n * TP + sig] & 0xffffffffull);
  }
  __syncthreads();
  for (int j = 0; j < 18; ++j) {
    const int c = tid * 2;
    const float* src = cb + (size_t)idxs[j] * CDIM + c;
    rows[j][c] = src[0];
    rows[j][c + 1] = src[1];
  }
  __syncthreads();

  const int cg = tid >> 1, half = tid & 1;
  const int c0 = cg * 4;
  f32x4 inva[4], invb[4];
#pragma unroll
  for (int j = 0; j < 4; ++j) {
    const float* p = pin + (size_t)n * (CDIM * TP) + (size_t)(c0 + j) * TP +
                     s0 + half * 8;
    inva[j] = *(const f32x4*)p;
    invb[j] = *(const f32x4*)(p + 4);
  }

  float pv[4][4];
#pragma unroll
  for (int q = 0; q < 4; ++q) {
    const int e = half * 8 + 2 * q;
    const int sa = e + 1, sb = e + 2;
    f32x4 Rm = *(const f32x4*)&rows[sa - 1][c0];
    f32x4 Rc = *(const f32x4*)&rows[sa][c0];
    f32x4 Rp = *(const f32x4*)&rows[sb][c0];
    f32x4 Rpp = *(const f32x4*)&rows[sb + 1][c0];
    f32x4 ua = 0.125f * (Rm + Rp) + 0.75f * Rc;
    f32x4 ub = 0.125f * (Rc + Rpp) + 0.75f * Rp;
#pragma unroll
    for (int j = 0; j < 4; ++j) {
      const int l = 2 * q;
      const float ia = (l < 4) ? inva[j][l] : invb[j][l - 4];
      const float ib = (l + 1 < 4) ? inva[j][l + 1] : invb[j][l - 3];
      pv[j][q] = ((ia - ua[j]) + (ib - ub[j])) * 0.5f;
    }
  }

  if constexpr (WPOOL) {
#pragma unroll
    for (int j = 0; j < 4; ++j) {
      f32x4 o = {pv[j][0], pv[j][1], pv[j][2], pv[j][3]};
      *(f32x4*)(pout + (size_t)n * (CDIM * TO) + (size_t)(c0 + j) * TO + o0 +
                half * 4) = o;
    }
  }
  const int kc = c0 >> 6, kbyte = (c0 & 63) * 2;
#pragma unroll
  for (int q = 0; q < 4; ++q) {
    const int m = n * TO + o0 + half * 4 + q;
    i32x2 o = {(int)pack2ch(pv[0][q], pv[1][q]),
               (int)pack2ch(pv[2][q], pv[3][q])};
    *(i32x2*)(a_next + (((size_t)((m >> 7) * 8 + kc)) << 14) +
              tile_addr(m & 127, kbyte)) = o;
  }
}

// ---------------------------------------------------------------------------
// final: one full-res pass: 4 per-stage losses + f_hat.
__global__ __launch_bounds__(256) void final_kernel(
    const float* __restrict__ x, float* __restrict__ out,
    const float* __restrict__ cb, const u64* __restrict__ packed,
    float* __restrict__ lossPart) {
  __shared__ float rows1[16][516];
  __shared__ int idx1[16];
  __shared__ float red[4][4];
  const int tid = threadIdx.x;
  const int blk = blockIdx.x;  // 16 n x 128 tiles
  const int n = blk >> 7;
  const int t0 = (blk & 127) * 16;
  if (tid < 16)
    idx1[tid] = (int)(packed[(size_t)n * TDIM + t0 + tid] & 0xffffffffull);
  __syncthreads();
  {
    const int rj = tid >> 4, c16 = tid & 15;
    const float* src = cb + (size_t)idx1[rj] * CDIM;
#pragma unroll
    for (int q = 0; q < 8; ++q) {
      const int c = c16 * 4 + q * 64;
      *(f32x4*)&rows1[rj][c] = *(const f32x4*)(src + c);
    }
  }
  __syncthreads();

  const int cg = tid >> 1, half = tid & 1;
  const int c0 = cg * 4;
  const int tb = t0 + half * 8;
  const int b2 = tb >> 1, b4 = tb >> 2, m8 = tb >> 3;
  const u64* ip2 = packed + 32768 + (size_t)n * 1024;
  const u64* ip4 = packed + 49152 + (size_t)n * 512;
  const u64* ip8 = packed + 57344 + (size_t)n * 256;

  f32x4 R2[6], R4[4], R8[3];
#pragma unroll
  for (int k = 0; k < 6; ++k) {
    const int s = iclamp(b2 - 1 + k, 0, 1023);
    R2[k] = *(const f32x4*)(
        cb + (size_t)(u32)(ip2[s] & 0xffffffffull) * CDIM + c0);
  }
#pragma unroll
  for (int k = 0; k < 4; ++k) {
    const int s = iclamp(b4 - 1 + k, 0, 511);
    R4[k] = *(const f32x4*)(
        cb + (size_t)(u32)(ip4[s] & 0xffffffffull) * CDIM + c0);
  }
#pragma unroll
  for (int k = 0; k < 3; ++k) {
    const int s = iclamp(m8 - 1 + k, 0, 255);
    R8[k] = *(const f32x4*)(
        cb + (size_t)(u32)(ip8[s] & 0xffffffffull) * CDIM + c0);
  }

  const size_t xbase = (size_t)n * (CDIM * TDIM) + (size_t)c0 * TDIM + tb;
  f32x4 xa[4], xb[4], fa[4], fb[4];
#pragma unroll
  for (int j = 0; j < 4; ++j) {
    xa[j] = *(const f32x4*)(x + xbase + (size_t)j * TDIM);
    xb[j] = *(const f32x4*)(x + xbase + (size_t)j * TDIM + 4);
  }

  const int s2s[8] = {0, 1, 1, 2, 2, 3, 3, 4};
  const float w2s[8] = {0.75f, 0.25f, 0.75f, 0.25f, 0.75f, 0.25f, 0.75f, 0.25f};
  const int s4s[8] = {0, 0, 1, 1, 1, 1, 2, 2};
  const float w4s[8] = {0.625f, 0.875f, 0.125f, 0.375f,
                        0.625f, 0.875f, 0.125f, 0.375f};
  const int s8s[8] = {0, 0, 0, 0, 1, 1, 1, 1};
  const float w8s[8] = {0.5625f, 0.6875f, 0.8125f, 0.9375f,
                        0.0625f, 0.1875f, 0.3125f, 0.4375f};

  float ss1 = 0.f, ss2 = 0.f, ss3 = 0.f, ss4 = 0.f;
#pragma unroll
  for (int tt = 0; tt < 8; ++tt) {
    f32x4 ru1 = *(const f32x4*)&rows1[half * 8 + tt][c0];
    f32x4 u2 = R2[s2s[tt]] * (1.f - w2s[tt]) + R2[s2s[tt] + 1] * w2s[tt];
    f32x4 u4 = R4[s4s[tt]] * (1.f - w4s[tt]) + R4[s4s[tt] + 1] * w4s[tt];
    f32x4 u8 = R8[s8s[tt]] * (1.f - w8s[tt]) + R8[s8s[tt] + 1] * w8s[tt];
    f32x4 xv;
#pragma unroll
    for (int j = 0; j < 4; ++j) xv[j] = (tt < 4) ? xa[j][tt] : xb[j][tt - 4];
    f32x4 r1 = xv - ru1;
    f32x4 r2 = r1 - u2;
    f32x4 r3 = r2 - u4;
    f32x4 r4 = r3 - u8;
#pragma unroll
    for (int j = 0; j < 4; ++j) {
      ss1 += r1[j] * r1[j];
      ss2 += r2[j] * r2[j];
      ss3 += r3[j] * r3[j];
      ss4 += r4[j] * r4[j];
    }
    f32x4 fh = xv - r4;
#pragma unroll
    for (int j = 0; j < 4; ++j) {
      if (tt < 4)
        fa[j][tt] = fh[j];
      else
        fb[j][tt - 4] = fh[j];
    }
  }
#pragma unroll
  for (int j = 0; j < 4; ++j) {
    *(f32x4*)(out + xbase + (size_t)j * TDIM) = fa[j];
    *(f32x4*)(out + xbase + (size_t)j * TDIM + 4) = fb[j];
  }

  float sv[4] = {ss1, ss2, ss3, ss4};
  const int w = tid >> 6, lane = tid & 63;
#pragma unroll
  for (int st = 0; st < 4; ++st) {
    float v = sv[st];
#pragma unroll
    for (int off = 32; off; off >>= 1) v += __shfl_down(v, off, 64);
    if (lane == 0) red[w][st] = v;
  }
  __syncthreads();
  if (tid < 4)
    lossPart[tid * 2048 + blk] =
        red[0][tid] + red[1][tid] + red[2][tid] + red[3][tid];
}

// ---------------------------------------------------------------------------
__global__ __launch_bounds__(256) void hist_kernel(const u64* __restrict__ packed,
                                                   int* __restrict__ hist) {
  const int i = blockIdx.x * 256 + threadIdx.x;  // 61440 total
  const int code = (int)(packed[i] & 0xFFFFFFFFull);
  atomicAdd(&hist[code], 1);
}

__global__ __launch_bounds__(256) void finalize_kernel(
    const float* __restrict__ lossPart, const int* __restrict__ hist,
    float* __restrict__ outTail) {
  __shared__ float red[4];
  const int tid = threadIdx.x;
  float s = 0.f;
  for (int i = tid; i < 4 * 2048; i += 256) s += lossPart[i];
#pragma unroll
  for (int off = 32; off; off >>= 1) s += __shfl_down(s, off, 64);
  if ((tid & 63) == 0) red[tid >> 6] = s;
  __syncthreads();
  const float loss =
      (red[0] + red[1] + red[2] + red[3]) * (1.0f / (4.0f * 16777216.0f));
  __syncthreads();
  float e = 0.f;
  for (int k = tid; k < KCODE; k += 256) {
    float p = (float)hist[k] * (1.0f / 61440.0f);
    e += p * logf(p + 1e-7f);
  }
#pragma unroll
  for (int off = 32; off; off >>= 1) e += __shfl_down(e, off, 64);
  if ((tid & 63) == 0) red[tid >> 6] = e;
  __syncthreads();
  if (tid == 0) {
    outTail[0] = loss;
    outTail[1] = expf(-(red[0] + red[1] + red[2] + red[3]));
  }
}

// ---------------------------------------------------------------------------
extern "C" void kernel_launch(void* const* d_in, const int* in_sizes, int n_in,
                              void* d_out, int out_size, void* d_ws,
                              size_t ws_size, hipStream_t stream) {
  const float* x = (const float*)d_in[0];
  const float* cb = (const float*)d_in[1];
  float* out = (float*)d_out;

  char* ws = (char*)d_ws;
  u64* packed = (u64*)ws;                   // 491520 B
  float* csq = (float*)(ws + 491520);       // 4096 B
  int* hist = (int*)(ws + 495616);          // 4096 B
  float* lossPart = (float*)(ws + 499712);  // 32768 B (4 x 2048)
  char* cb_pack = ws + 565248;              // 1 MiB
  char* a2 = ws + (2ull << 20);             // 16 MiB
  char* a4 = ws + (18ull << 20);            // 8 MiB
  char* a8 = ws + (26ull << 20);            // 4 MiB

  hipMemsetAsync(packed, 0xFF, (size_t)M_TOTAL * 8, stream);
  hipMemsetAsync(hist, 0, KCODE * sizeof(int), stream);
  csq_kernel<<<KCODE, 64, 0, stream>>>(cb, csq);
  cbprep_kernel<<<256, 256, 0, stream>>>(cb, cb_pack);

  u64* p1 = packed;          // 32768 rows (t_s=2048)
  u64* p2 = packed + 32768;  // 16384 rows
  u64* p4 = packed + 49152;  //  8192 rows
  u64* p8 = packed + 57344;  //  4096 rows

  // d_out region reuse: A1 (32MB) until gemm1; then poolr2 [0,32MB) +
  // poolr4 [32,48MB); finally f_hat overwrites everything.
  char* a1 = (char*)out;
  float* poolr2 = out;            // 16*512*1024 f32 = 32 MB
  float* poolr4 = out + 8388608;  // 16*512*512 f32 = 16 MB

  xprep_kernel<<<4096, 256, 0, stream>>>(x, a1);
  gemm_argmin_packed<<<dim3(256, 8), 256, 0, stream>>>(a1, cb_pack, csq, p1);
  pack2_kernel<<<2048, 256, 0, stream>>>(x, cb, packed, a2, poolr2);
  gemm_argmin_packed<<<dim3(128, 8), 256, 0, stream>>>(a2, cb_pack, csq, p2);
  packN_kernel<1024, true>
      <<<1024, 256, 0, stream>>>(poolr2, cb, packed, a4, poolr4);
  gemm_argmin_packed<<<dim3(64, 8), 256, 0, stream>>>(a4, cb_pack, csq, p4);
  packN_kernel<512, false>
      <<<512, 256, 0, stream>>>(poolr4, cb, packed, a8, nullptr);
  gemm_argmin_packed<<<dim3(32, 8), 256, 0, stream>>>(a8, cb_pack, csq, p8);
  final_kernel<<<2048, 256, 0, stream>>>(x, out, cb, packed, lossPart);

  hist_kernel<<<240, 256, 0, stream>>>(packed, hist);
  finalize_kernel<<<1, 256, 0, stream>>>(lossPart, hist, out + FH_ELEMS);
}

// Round 7
// 270.330 us; speedup vs baseline: 2.0829x; 1.1769x over previous
//
#include <hip/hip_runtime.h>

#define CDIM 512
#define TDIM 2048
#define KCODE 1024
#define NTOT 16
#define FH_ELEMS (NTOT * CDIM * TDIM)   // 16777216
#define M_TOTAL 61440                   // 16*(2048+1024+512+256)

typedef unsigned long long u64;
typedef unsigned int u32;
typedef __attribute__((ext_vector_type(8))) short s16x8;
typedef __attribute__((ext_vector_type(4))) float f32x4;
typedef __attribute__((ext_vector_type(4))) int i32x4;
typedef __attribute__((ext_vector_type(2))) int i32x2;

__device__ __forceinline__ u64 umin64(u64 a, u64 b) { return a < b ? a : b; }

// round-to-nearest-even fp32 -> bf16 bits
__device__ __forceinline__ u32 bf16_rne(float f) {
  u32 u = __float_as_uint(f);
  return (u + 0x7fffu + ((u >> 16) & 1u)) >> 16;
}
// pack two consecutive channels into one u32 (low16 = even channel)
__device__ __forceinline__ u32 pack2ch(float v0, float v1) {
  return bf16_rne(v0) | (bf16_rne(v1) << 16);
}
// byte offset of (m_local row, kbyte) inside a 16KB tile, XOR-swizzled
__device__ __forceinline__ int tile_addr(int ml, int kbyte) {
  return (ml * 128 + kbyte) ^ ((ml & 7) << 4);
}
__device__ __forceinline__ int iclamp(int v, int lo, int hi) {
  return v < lo ? lo : (v > hi ? hi : v);
}

// ---------------------------------------------------------------------------
// csq[k] = sum(codebook[k]^2)
__global__ __launch_bounds__(64) void csq_kernel(const float* __restrict__ cb,
                                                 float* __restrict__ csq) {
  const int code = blockIdx.x;
  const int t = threadIdx.x;
  const float* row = cb + (size_t)code * CDIM;
  float s = 0.f;
#pragma unroll
  for (int q = 0; q < 2; ++q) {
    float4 v = *(const float4*)(row + (t * 2 + q) * 4);
    s += v.x * v.x + v.y * v.y + v.z * v.z + v.w * v.w;
  }
#pragma unroll
  for (int off = 32; off; off >>= 1) s += __shfl_down(s, off, 64);
  if (t == 0) csq[code] = s;
}

// ---------------------------------------------------------------------------
// Pre-pack codebook bf16: tiled [code_tile 0..7][kc 0..7][16KB], XOR-swizzled.
__global__ __launch_bounds__(256) void cbprep_kernel(const float* __restrict__ cb,
                                                     char* __restrict__ cb_pack) {
  const int g = blockIdx.x * 256 + threadIdx.x;  // 65536 threads x 16B = 1MB
  const int tile = g >> 10;
  const int L = (g & 1023) * 16;
  const int nt = tile >> 3, kc = tile & 7;
  const int code_local = L >> 7;
  const int kbyte = (L & 127) ^ ((code_local & 7) << 4);
  const int code = nt * 128 + code_local;
  const int c0 = kc * 64 + (kbyte >> 1);
  f32x4 va = *(const f32x4*)(cb + (size_t)code * CDIM + c0);
  f32x4 vb = *(const f32x4*)(cb + (size_t)code * CDIM + c0 + 4);
  i32x4 o = {(int)pack2ch(va[0], va[1]), (int)pack2ch(va[2], va[3]),
             (int)pack2ch(vb[0], vb[1]), (int)pack2ch(vb[2], vb[3])};
  *(i32x4*)(cb_pack + (size_t)g * 16) = o;
}

// ---------------------------------------------------------------------------
// A1 pack. Block = (n, kc, 256 t); thread = 16 channels x 4 t.
// Reads coalesced along t; every 128B tile-row completed inside one block
// (4 cq waves) -> single-L2 write merge, no HBM write amplification.
__global__ __launch_bounds__(256) void xprep_kernel(const float* __restrict__ x,
                                                    char* __restrict__ a1) {
  const int tid = threadIdx.x;
  const int lane = tid & 63, cq = tid >> 6;
  const int blk = blockIdx.x;  // [n:16][kc:8][tb:8]
  const int tb = blk & 7;
  const int kc = (blk >> 3) & 7;
  const int n = blk >> 6;
  const int c0 = kc * 64 + cq * 16;
  const int t0 = tb * 256 + lane * 4;
  const float* xp = x + (size_t)n * (CDIM * TDIM) + (size_t)c0 * TDIM + t0;
  u32 pk[4][8];
#pragma unroll
  for (int jp = 0; jp < 8; ++jp) {
    f32x4 v0 = *(const f32x4*)(xp + (size_t)(2 * jp) * TDIM);
    f32x4 v1 = *(const f32x4*)(xp + (size_t)(2 * jp + 1) * TDIM);
#pragma unroll
    for (int tt = 0; tt < 4; ++tt) pk[tt][jp] = pack2ch(v0[tt], v1[tt]);
  }
  const int kbyte = cq * 32;
#pragma unroll
  for (int tt = 0; tt < 4; ++tt) {
    const int m = n * TDIM + t0 + tt;
    const size_t tbase = ((size_t)((m >> 7) * 8 + kc)) << 14;
    i32x4 o1 = {(int)pk[tt][0], (int)pk[tt][1], (int)pk[tt][2], (int)pk[tt][3]};
    i32x4 o2 = {(int)pk[tt][4], (int)pk[tt][5], (int)pk[tt][6], (int)pk[tt][7]};
    *(i32x4*)(a1 + tbase + tile_addr(m & 127, kbyte)) = o1;
    *(i32x4*)(a1 + tbase + tile_addr(m & 127, kbyte + 16)) = o2;
  }
}

// ---------------------------------------------------------------------------
// Scale-independent MFMA distance GEMM + argmin; both operands pre-packed bf16.
// 1D grid nx*8, XCD-chunked decode: all 8 code-tiles of one m-tile run on the
// same XCD consecutively -> A-tile + cb_pack stay L2-resident.
__global__ __launch_bounds__(256, 4) void gemm_argmin_packed(
    const char* __restrict__ a_pack,   // [m_tiles][8][16KB]
    const char* __restrict__ cb_pack,  // [8][8][16KB]
    const float* __restrict__ csq,
    u64* __restrict__ packed) {
  __shared__ __align__(16) char smem[16384 * 2 + 512];
  char* xs = smem;
  char* cbs = smem + 16384;
  float* csq_s = (float*)(smem + 32768);

  const int id = blockIdx.x;
  const int nxp = gridDim.x >> 6;  // nx/8
  const int xcd = id & 7;
  const int r = id >> 3;
  const int bx = xcd * nxp + (r >> 3);
  const int by = r & 7;

  const int tid = threadIdx.x;
  const int lane = tid & 63;
  const int w = tid >> 6;
  const int row_base = bx * 128;
  const int code_base = by * 128;
  if (tid < 128) csq_s[tid] = csq[code_base + tid];

  const f32x4 zero = {0.f, 0.f, 0.f, 0.f};
  f32x4 acc[4][4];
#pragma unroll
  for (int fc = 0; fc < 4; ++fc)
#pragma unroll
    for (int fm = 0; fm < 4; ++fm) acc[fc][fm] = zero;

  const size_t a0 = ((size_t)bx * 8) << 14;
  const size_t b0 = ((size_t)by * 8) << 14;
  const int wc = w >> 1, wm = w & 1;

  for (int kc = 0; kc < 8; ++kc) {
    __syncthreads();
    const char* gA = a_pack + a0 + ((size_t)kc << 14);
    const char* gB = cb_pack + b0 + ((size_t)kc << 14);
    char* la = xs + (w << 10);
    char* lb = cbs + (w << 10);
#pragma unroll
    for (int p = 0; p < 4; ++p) {
      __builtin_amdgcn_global_load_lds(
          (const __attribute__((address_space(1))) u32*)(gA + (p << 12) + (tid << 4)),
          (__attribute__((address_space(3))) u32*)(la + (p << 12)), 16, 0, 0);
      __builtin_amdgcn_global_load_lds(
          (const __attribute__((address_space(1))) u32*)(gB + (p << 12) + (tid << 4)),
          (__attribute__((address_space(3))) u32*)(lb + (p << 12)), 16, 0, 0);
    }
    __syncthreads();
#pragma unroll
    for (int ks = 0; ks < 2; ++ks) {
      s16x8 af[4], bq[4];
#pragma unroll
      for (int fc = 0; fc < 4; ++fc) {
        const int row = wc * 64 + fc * 16 + (lane & 15);
        af[fc] = *(const s16x8*)(cbs + tile_addr(row, ks * 64 + (lane >> 4) * 16));
      }
#pragma unroll
      for (int fm = 0; fm < 4; ++fm) {
        const int row = wm * 64 + fm * 16 + (lane & 15);
        bq[fm] = *(const s16x8*)(xs + tile_addr(row, ks * 64 + (lane >> 4) * 16));
      }
#pragma unroll
      for (int fc = 0; fc < 4; ++fc)
#pragma unroll
        for (int fm = 0; fm < 4; ++fm)
          acc[fc][fm] = __builtin_amdgcn_mfma_f32_16x16x32_bf16(
              af[fc], bq[fm], acc[fc][fm], 0, 0, 0);
    }
  }

  u64 best[4] = {~0ull, ~0ull, ~0ull, ~0ull};
#pragma unroll
  for (int fc = 0; fc < 4; ++fc) {
#pragma unroll
    for (int r4 = 0; r4 < 4; ++r4) {
      const int cl = wc * 64 + fc * 16 + (lane >> 4) * 4 + r4;
      const float cs = csq_s[cl];
      const u64 codebits = (u32)(code_base + cl);
#pragma unroll
      for (int fm = 0; fm < 4; ++fm) {
        float d = fmaf(-2.0f, acc[fc][fm][r4], cs);
        u32 u = __float_as_uint(d);
        u = (u & 0x80000000u) ? ~u : (u | 0x80000000u);
        best[fm] = umin64(best[fm], ((u64)u << 32) | codebits);
      }
    }
  }
#pragma unroll
  for (int fm = 0; fm < 4; ++fm) {
    u64 b = best[fm];
#pragma unroll
    for (int off = 16; off < 64; off <<= 1) {
      u32 lo = (u32)b, hi = (u32)(b >> 32);
      lo = (u32)__shfl_xor((int)lo, off, 64);
      hi = (u32)__shfl_xor((int)hi, off, 64);
      b = umin64(b, ((u64)hi << 32) | lo);
    }
    if ((lane >> 4) == 0)
      atomicMin(&packed[row_base + wm * 64 + fm * 16 + (lane & 15)], b);
  }
}

// ---------------------------------------------------------------------------
// pack2: A2 = pool2(x - up1) + poolr2 f32 ([n][tau][c] layout).
__global__ __launch_bounds__(256) void pack2_kernel(
    const float* __restrict__ x, const float* __restrict__ cb,
    const u64* __restrict__ packed, char* __restrict__ a2,
    float* __restrict__ poolr2) {
  __shared__ float rows1[16][516];
  __shared__ int idx1[16];
  const int tid = threadIdx.x;
  const int blk = blockIdx.x;  // 16 n x 128 tiles
  const int n = blk >> 7;
  const int tau0 = (blk & 127) * 8;
  const int tb = tau0 * 2;  // full-res t in [tb, tb+16)
  if (tid < 16)
    idx1[tid] = (int)(packed[(size_t)n * TDIM + tb + tid] & 0xffffffffull);
  __syncthreads();
  {
    const int rj = tid >> 4, c16 = tid & 15;
    const float* src = cb + (size_t)idx1[rj] * CDIM;
#pragma unroll
    for (int q = 0; q < 8; ++q) {
      const int c = c16 * 4 + q * 64;
      *(f32x4*)&rows1[rj][c] = *(const f32x4*)(src + c);
    }
  }
  __syncthreads();

  const int cg = tid >> 1, half = tid & 1;
  const int c0 = cg * 4;
  const int tl0 = half * 8;  // local t base
  const size_t xbase =
      (size_t)n * (CDIM * TDIM) + (size_t)c0 * TDIM + tb + tl0;

  f32x4 ru[8];
#pragma unroll
  for (int t = 0; t < 8; ++t) ru[t] = *(const f32x4*)&rows1[tl0 + t][c0];

  float p2[4][4];  // [c][q]
#pragma unroll
  for (int j = 0; j < 4; ++j) {
    f32x4 xa = *(const f32x4*)(x + xbase + (size_t)j * TDIM);
    f32x4 xb = *(const f32x4*)(x + xbase + (size_t)j * TDIM + 4);
#pragma unroll
    for (int q = 0; q < 4; ++q) {
      const float e0 = (q < 2) ? xa[2 * q] : xb[2 * q - 4];
      const float e1 = (q < 2) ? xa[2 * q + 1] : xb[2 * q - 3];
      const float r0 = e0 - ru[2 * q][j];
      const float r1 = e1 - ru[2 * q + 1][j];
      p2[j][q] = (r0 + r1) * 0.5f;
    }
  }
  // poolr2 [n][tau][c]: lanes (cg) coalesced along c per tau
#pragma unroll
  for (int q = 0; q < 4; ++q) {
    f32x4 o = {p2[0][q], p2[1][q], p2[2][q], p2[3][q]};
    *(f32x4*)(poolr2 + (size_t)n * (1024 * CDIM) +
              (size_t)(tau0 + half * 4 + q) * CDIM + c0) = o;
  }
  // a2 pack (row pieces completed within the wave)
  const int kc = c0 >> 6, kbyte = (c0 & 63) * 2;
#pragma unroll
  for (int q = 0; q < 4; ++q) {
    const int m = n * 1024 + tau0 + half * 4 + q;
    i32x2 o = {(int)pack2ch(p2[0][q], p2[1][q]),
               (int)pack2ch(p2[2][q], p2[3][q])};
    *(i32x2*)(a2 + (((size_t)((m >> 7) * 8 + kc)) << 14) +
              tile_addr(m & 127, kbyte)) = o;
  }
}

// ---------------------------------------------------------------------------
// packN: pool chain at coarse res; pin/pout layout [n][tau][c].
template <int TP, bool WPOOL>
__global__ __launch_bounds__(256) void packN_kernel(
    const float* __restrict__ pin, const float* __restrict__ cb,
    const u64* __restrict__ packed, char* __restrict__ a_next,
    float* __restrict__ pout) {
  constexpr int OFF = (TP == 1024) ? 32768 : 49152;  // scale-2 / scale-4 idx
  constexpr int TILES = TP / 16;
  constexpr int TO = TP / 2;
  __shared__ float rows[18][516];
  __shared__ int idxs[18];
  const int tid = threadIdx.x;
  const int blk = blockIdx.x;  // 16 n x TILES
  const int n = blk / TILES;
  const int o0 = (blk % TILES) * 8;  // output tau base
  const int s0 = o0 * 2;             // input sigma base
  if (tid < 18) {
    const int sig = iclamp(s0 - 1 + tid, 0, TP - 1);
    idxs[tid] = (int)(packed[OFF + (size_t)n * TP + sig] & 0xffffffffull);
  }
  __syncthreads();
  for (int j = 0; j < 18; ++j) {
    const int c = tid * 2;
    const float* src = cb + (size_t)idxs[j] * CDIM + c;
    rows[j][c] = src[0];
    rows[j][c + 1] = src[1];
  }
  __syncthreads();

  const int cg = tid >> 1, half = tid & 1;
  const int c0 = cg * 4;
  // inv[l] = pool_P(r)[n][s0+half*8+l][c0..c0+3]; coalesced along c
  f32x4 inv[8];
#pragma unroll
  for (int l = 0; l < 8; ++l)
    inv[l] = *(const f32x4*)(pin + (size_t)n * (TP * CDIM) +
                             (size_t)(s0 + half * 8 + l) * CDIM + c0);

  float pv[4][4];
#pragma unroll
  for (int q = 0; q < 4; ++q) {
    const int e = half * 8 + 2 * q;
    const int sa = e + 1, sb = e + 2;
    f32x4 Rm = *(const f32x4*)&rows[sa - 1][c0];
    f32x4 Rc = *(const f32x4*)&rows[sa][c0];
    f32x4 Rp = *(const f32x4*)&rows[sb][c0];
    f32x4 Rpp = *(const f32x4*)&rows[sb + 1][c0];
    f32x4 ua = 0.125f * (Rm + Rp) + 0.75f * Rc;
    f32x4 ub = 0.125f * (Rc + Rpp) + 0.75f * Rp;
#pragma unroll
    for (int j = 0; j < 4; ++j)
      pv[j][q] = ((inv[2 * q][j] - ua[j]) + (inv[2 * q + 1][j] - ub[j])) * 0.5f;
  }

  if constexpr (WPOOL) {
#pragma unroll
    for (int q = 0; q < 4; ++q) {
      f32x4 o = {pv[0][q], pv[1][q], pv[2][q], pv[3][q]};
      *(f32x4*)(pout + (size_t)n * (TO * CDIM) +
                (size_t)(o0 + half * 4 + q) * CDIM + c0) = o;
    }
  }
  const int kc = c0 >> 6, kbyte = (c0 & 63) * 2;
#pragma unroll
  for (int q = 0; q < 4; ++q) {
    const int m = n * TO + o0 + half * 4 + q;
    i32x2 o = {(int)pack2ch(pv[0][q], pv[1][q]),
               (int)pack2ch(pv[2][q], pv[3][q])};
    *(i32x2*)(a_next + (((size_t)((m >> 7) * 8 + kc)) << 14) +
              tile_addr(m & 127, kbyte)) = o;
  }
}

// ---------------------------------------------------------------------------
// final: one full-res pass: 4 per-stage losses + f_hat.
__global__ __launch_bounds__(256) void final_kernel(
    const float* __restrict__ x, float* __restrict__ out,
    const float* __restrict__ cb, const u64* __restrict__ packed,
    float* __restrict__ lossPart) {
  __shared__ float rows1[16][516];
  __shared__ int idx1[16];
  __shared__ float red[4][4];
  const int tid = threadIdx.x;
  const int blk = blockIdx.x;  // 16 n x 128 tiles
  const int n = blk >> 7;
  const int t0 = (blk & 127) * 16;
  if (tid < 16)
    idx1[tid] = (int)(packed[(size_t)n * TDIM + t0 + tid] & 0xffffffffull);
  __syncthreads();
  {
    const int rj = tid >> 4, c16 = tid & 15;
    const float* src = cb + (size_t)idx1[rj] * CDIM;
#pragma unroll
    for (int q = 0; q < 8; ++q) {
      const int c = c16 * 4 + q * 64;
      *(f32x4*)&rows1[rj][c] = *(const f32x4*)(src + c);
    }
  }
  __syncthreads();

  const int cg = tid >> 1, half = tid & 1;
  const int c0 = cg * 4;
  const int tb = t0 + half * 8;
  const int b2 = tb >> 1, b4 = tb >> 2, m8 = tb >> 3;
  const u64* ip2 = packed + 32768 + (size_t)n * 1024;
  const u64* ip4 = packed + 49152 + (size_t)n * 512;
  const u64* ip8 = packed + 57344 + (size_t)n * 256;

  f32x4 R2[6], R4[4], R8[3];
#pragma unroll
  for (int k = 0; k < 6; ++k) {
    const int s = iclamp(b2 - 1 + k, 0, 1023);
    R2[k] = *(const f32x4*)(
        cb + (size_t)(u32)(ip2[s] & 0xffffffffull) * CDIM + c0);
  }
#pragma unroll
  for (int k = 0; k < 4; ++k) {
    const int s = iclamp(b4 - 1 + k, 0, 511);
    R4[k] = *(const f32x4*)(
        cb + (size_t)(u32)(ip4[s] & 0xffffffffull) * CDIM + c0);
  }
#pragma unroll
  for (int k = 0; k < 3; ++k) {
    const int s = iclamp(m8 - 1 + k, 0, 255);
    R8[k] = *(const f32x4*)(
        cb + (size_t)(u32)(ip8[s] & 0xffffffffull) * CDIM + c0);
  }

  const size_t xbase = (size_t)n * (CDIM * TDIM) + (size_t)c0 * TDIM + tb;
  f32x4 xa[4], xb[4], fa[4], fb[4];
#pragma unroll
  for (int j = 0; j < 4; ++j) {
    xa[j] = *(const f32x4*)(x + xbase + (size_t)j * TDIM);
    xb[j] = *(const f32x4*)(x + xbase + (size_t)j * TDIM + 4);
  }

  const int s2s[8] = {0, 1, 1, 2, 2, 3, 3, 4};
  const float w2s[8] = {0.75f, 0.25f, 0.75f, 0.25f, 0.75f, 0.25f, 0.75f, 0.25f};
  const int s4s[8] = {0, 0, 1, 1, 1, 1, 2, 2};
  const float w4s[8] = {0.625f, 0.875f, 0.125f, 0.375f,
                        0.625f, 0.875f, 0.125f, 0.375f};
  const int s8s[8] = {0, 0, 0, 0, 1, 1, 1, 1};
  const float w8s[8] = {0.5625f, 0.6875f, 0.8125f, 0.9375f,
                        0.0625f, 0.1875f, 0.3125f, 0.4375f};

  float ss1 = 0.f, ss2 = 0.f, ss3 = 0.f, ss4 = 0.f;
#pragma unroll
  for (int tt = 0; tt < 8; ++tt) {
    f32x4 ru1 = *(const f32x4*)&rows1[half * 8 + tt][c0];
    f32x4 u2 = R2[s2s[tt]] * (1.f - w2s[tt]) + R2[s2s[tt] + 1] * w2s[tt];
    f32x4 u4 = R4[s4s[tt]] * (1.f - w4s[tt]) + R4[s4s[tt] + 1] * w4s[tt];
    f32x4 u8 = R8[s8s[tt]] * (1.f - w8s[tt]) + R8[s8s[tt] + 1] * w8s[tt];
    f32x4 xv;
#pragma unroll
    for (int j = 0; j < 4; ++j) xv[j] = (tt < 4) ? xa[j][tt] : xb[j][tt - 4];
    f32x4 r1 = xv - ru1;
    f32x4 r2 = r1 - u2;
    f32x4 r3 = r2 - u4;
    f32x4 r4 = r3 - u8;
#pragma unroll
    for (int j = 0; j < 4; ++j) {
      ss1 += r1[j] * r1[j];
      ss2 += r2[j] * r2[j];
      ss3 += r3[j] * r3[j];
      ss4 += r4[j] * r4[j];
    }
    f32x4 fh = xv - r4;
#pragma unroll
    for (int j = 0; j < 4; ++j) {
      if (tt < 4)
        fa[j][tt] = fh[j];
      else
        fb[j][tt - 4] = fh[j];
    }
  }
#pragma unroll
  for (int j = 0; j < 4; ++j) {
    *(f32x4*)(out + xbase + (size_t)j * TDIM) = fa[j];
    *(f32x4*)(out + xbase + (size_t)j * TDIM + 4) = fb[j];
  }

  float sv[4] = {ss1, ss2, ss3, ss4};
  const int w = tid >> 6, lane = tid & 63;
#pragma unroll
  for (int st = 0; st < 4; ++st) {
    float v = sv[st];
#pragma unroll
    for (int off = 32; off; off >>= 1) v += __shfl_down(v, off, 64);
    if (lane == 0) red[w][st] = v;
  }
  __syncthreads();
  if (tid < 4)
    lossPart[tid * 2048 + blk] =
        red[0][tid] + red[1][tid] + red[2][tid] + red[3][tid];
}

// ---------------------------------------------------------------------------
__global__ __launch_bounds__(256) void hist_kernel(const u64* __restrict__ packed,
                                                   int* __restrict__ hist) {
  const int i = blockIdx.x * 256 + threadIdx.x;  // 61440 total
  const int code = (int)(packed[i] & 0xFFFFFFFFull);
  atomicAdd(&hist[code], 1);
}

__global__ __launch_bounds__(256) void finalize_kernel(
    const float* __restrict__ lossPart, const int* __restrict__ hist,
    float* __restrict__ outTail) {
  __shared__ float red[4];
  const int tid = threadIdx.x;
  float s = 0.f;
  for (int i = tid; i < 4 * 2048; i += 256) s += lossPart[i];
#pragma unroll
  for (int off = 32; off; off >>= 1) s += __shfl_down(s, off, 64);
  if ((tid & 63) == 0) red[tid >> 6] = s;
  __syncthreads();
  const float loss =
      (red[0] + red[1] + red[2] + red[3]) * (1.0f / (4.0f * 16777216.0f));
  __syncthreads();
  float e = 0.f;
  for (int k = tid; k < KCODE; k += 256) {
    float p = (float)hist[k] * (1.0f / 61440.0f);
    e += p * logf(p + 1e-7f);
  }
#pragma unroll
  for (int off = 32; off; off >>= 1) e += __shfl_down(e, off, 64);
  if ((tid & 63) == 0) red[tid >> 6] = e;
  __syncthreads();
  if (tid == 0) {
    outTail[0] = loss;
    outTail[1] = expf(-(red[0] + red[1] + red[2] + red[3]));
  }
}

// ---------------------------------------------------------------------------
extern "C" void kernel_launch(void* const* d_in, const int* in_sizes, int n_in,
                              void* d_out, int out_size, void* d_ws,
                              size_t ws_size, hipStream_t stream) {
  const float* x = (const float*)d_in[0];
  const float* cb = (const float*)d_in[1];
  float* out = (float*)d_out;

  char* ws = (char*)d_ws;
  u64* packed = (u64*)ws;                   // 491520 B
  float* csq = (float*)(ws + 491520);       // 4096 B
  int* hist = (int*)(ws + 495616);          // 4096 B
  float* lossPart = (float*)(ws + 499712);  // 32768 B (4 x 2048)
  char* cb_pack = ws + 565248;              // 1 MiB
  char* a2 = ws + (2ull << 20);             // 16 MiB
  char* a4 = ws + (18ull << 20);            // 8 MiB
  char* a8 = ws + (26ull << 20);            // 4 MiB

  hipMemsetAsync(packed, 0xFF, (size_t)M_TOTAL * 8, stream);
  hipMemsetAsync(hist, 0, KCODE * sizeof(int), stream);
  csq_kernel<<<KCODE, 64, 0, stream>>>(cb, csq);
  cbprep_kernel<<<256, 256, 0, stream>>>(cb, cb_pack);

  u64* p1 = packed;          // 32768 rows (t_s=2048)
  u64* p2 = packed + 32768;  // 16384 rows
  u64* p4 = packed + 49152;  //  8192 rows
  u64* p8 = packed + 57344;  //  4096 rows

  // d_out region reuse: A1 (32MB) until gemm1; then poolr2 [0,32MB) +
  // poolr4 [32,48MB); finally f_hat overwrites everything.
  char* a1 = (char*)out;
  float* poolr2 = out;            // [n][1024][512] f32 = 32 MB
  float* poolr4 = out + 8388608;  // [n][512][512]  f32 = 16 MB

  xprep_kernel<<<1024, 256, 0, stream>>>(x, a1);
  gemm_argmin_packed<<<256 * 8, 256, 0, stream>>>(a1, cb_pack, csq, p1);
  pack2_kernel<<<2048, 256, 0, stream>>>(x, cb, packed, a2, poolr2);
  gemm_argmin_packed<<<128 * 8, 256, 0, stream>>>(a2, cb_pack, csq, p2);
  packN_kernel<1024, true>
      <<<1024, 256, 0, stream>>>(poolr2, cb, packed, a4, poolr4);
  gemm_argmin_packed<<<64 * 8, 256, 0, stream>>>(a4, cb_pack, csq, p4);
  packN_kernel<512, false>
      <<<512, 256, 0, stream>>>(poolr4, cb, packed, a8, nullptr);
  gemm_argmin_packed<<<32 * 8, 256, 0, stream>>>(a8, cb_pack, csq, p8);
  final_kernel<<<2048, 256, 0, stream>>>(x, out, cb, packed, lossPart);

  hist_kernel<<<240, 256, 0, stream>>>(packed, hist);
  finalize_kernel<<<1, 256, 0, stream>>>(lossPart, hist, out + FH_ELEMS);
}

// Round 9
// 242.271 us; speedup vs baseline: 2.3241x; 1.1158x over previous
//
#include <hip/hip_runtime.h>

#define CDIM 512
#define TDIM 2048
#define KCODE 1024
#define NTOT 16
#define FH_ELEMS (NTOT * CDIM * TDIM)   // 16777216
#define M_TOTAL 61440                   // 16*(2048+1024+512+256)

typedef unsigned long long u64;
typedef unsigned int u32;
typedef __attribute__((ext_vector_type(8))) short s16x8;
typedef __attribute__((ext_vector_type(4))) float f32x4;
typedef __attribute__((ext_vector_type(4))) int i32x4;
typedef __attribute__((ext_vector_type(2))) int i32x2;

__device__ __forceinline__ u64 umin64(u64 a, u64 b) { return a < b ? a : b; }

// round-to-nearest-even fp32 -> bf16 bits
__device__ __forceinline__ u32 bf16_rne(float f) {
  u32 u = __float_as_uint(f);
  return (u + 0x7fffu + ((u >> 16) & 1u)) >> 16;
}
// pack two consecutive channels into one u32 (low16 = even channel)
__device__ __forceinline__ u32 pack2ch(float v0, float v1) {
  return bf16_rne(v0) | (bf16_rne(v1) << 16);
}
// byte offset of (m_local row, kbyte) inside a 16KB tile, XOR-swizzled
__device__ __forceinline__ int tile_addr(int ml, int kbyte) {
  return (ml * 128 + kbyte) ^ ((ml & 7) << 4);
}
__device__ __forceinline__ int iclamp(int v, int lo, int hi) {
  return v < lo ? lo : (v > hi ? hi : v);
}

// ---------------------------------------------------------------------------
// csq[k] = sum(codebook[k]^2)
__global__ __launch_bounds__(64) void csq_kernel(const float* __restrict__ cb,
                                                 float* __restrict__ csq) {
  const int code = blockIdx.x;
  const int t = threadIdx.x;
  const float* row = cb + (size_t)code * CDIM;
  float s = 0.f;
#pragma unroll
  for (int q = 0; q < 2; ++q) {
    float4 v = *(const float4*)(row + (t * 2 + q) * 4);
    s += v.x * v.x + v.y * v.y + v.z * v.z + v.w * v.w;
  }
#pragma unroll
  for (int off = 32; off; off >>= 1) s += __shfl_down(s, off, 64);
  if (t == 0) csq[code] = s;
}

// ---------------------------------------------------------------------------
// Pre-pack codebook bf16: tiled [code_tile 0..7][kc 0..7][16KB], XOR-swizzled.
__global__ __launch_bounds__(256) void cbprep_kernel(const float* __restrict__ cb,
                                                     char* __restrict__ cb_pack) {
  const int g = blockIdx.x * 256 + threadIdx.x;  // 65536 threads x 16B = 1MB
  const int tile = g >> 10;
  const int L = (g & 1023) * 16;
  const int nt = tile >> 3, kc = tile & 7;
  const int code_local = L >> 7;
  const int kbyte = (L & 127) ^ ((code_local & 7) << 4);
  const int code = nt * 128 + code_local;
  const int c0 = kc * 64 + (kbyte >> 1);
  f32x4 va = *(const f32x4*)(cb + (size_t)code * CDIM + c0);
  f32x4 vb = *(const f32x4*)(cb + (size_t)code * CDIM + c0 + 4);
  i32x4 o = {(int)pack2ch(va[0], va[1]), (int)pack2ch(va[2], va[3]),
             (int)pack2ch(vb[0], vb[1]), (int)pack2ch(vb[2], vb[3])};
  *(i32x4*)(cb_pack + (size_t)g * 16) = o;
}

// ---------------------------------------------------------------------------
// A1 pack. Block = (n, kc, 256 t); thread = 16 channels x 4 t.
__global__ __launch_bounds__(256) void xprep_kernel(const float* __restrict__ x,
                                                    char* __restrict__ a1) {
  const int tid = threadIdx.x;
  const int lane = tid & 63, cq = tid >> 6;
  const int blk = blockIdx.x;  // [n:16][kc:8][tb:8]
  const int tb = blk & 7;
  const int kc = (blk >> 3) & 7;
  const int n = blk >> 6;
  const int c0 = kc * 64 + cq * 16;
  const int t0 = tb * 256 + lane * 4;
  const float* xp = x + (size_t)n * (CDIM * TDIM) + (size_t)c0 * TDIM + t0;
  u32 pk[4][8];
#pragma unroll
  for (int jp = 0; jp < 8; ++jp) {
    f32x4 v0 = *(const f32x4*)(xp + (size_t)(2 * jp) * TDIM);
    f32x4 v1 = *(const f32x4*)(xp + (size_t)(2 * jp + 1) * TDIM);
#pragma unroll
    for (int tt = 0; tt < 4; ++tt) pk[tt][jp] = pack2ch(v0[tt], v1[tt]);
  }
  const int kbyte = cq * 32;
#pragma unroll
  for (int tt = 0; tt < 4; ++tt) {
    const int m = n * TDIM + t0 + tt;
    const size_t tbase = ((size_t)((m >> 7) * 8 + kc)) << 14;
    i32x4 o1 = {(int)pk[tt][0], (int)pk[tt][1], (int)pk[tt][2], (int)pk[tt][3]};
    i32x4 o2 = {(int)pk[tt][4], (int)pk[tt][5], (int)pk[tt][6], (int)pk[tt][7]};
    *(i32x4*)(a1 + tbase + tile_addr(m & 127, kbyte)) = o1;
    *(i32x4*)(a1 + tbase + tile_addr(m & 127, kbyte + 16)) = o2;
  }
}

// ---------------------------------------------------------------------------
// 256x256 MFMA distance GEMM + argmin, 2-phase double-buffered LDS, single
// barrier per K-step (stage-early). 8 waves = 2(code) x 4(m). grid = nx*4,
// XCD-chunked so the 4 code-tiles of one m-tile share an XCD L2.
// LDS buffer layout: [0:32K) = x rows (m), [32K:64K) = codebook rows.
__global__ __launch_bounds__(512, 2) void gemm_argmin_packed(
    const char* __restrict__ a_pack,   // [m_tiles(128r)][8][16KB]
    const char* __restrict__ cb_pack,  // [8][8][16KB]
    const float* __restrict__ csq,
    u64* __restrict__ packed) {
  __shared__ __align__(16) char smem[131072 + 1024];
  float* csq_s = (float*)(smem + 131072);

  const int id = blockIdx.x;
  const int nxq = gridDim.x >> 5;  // nx/8   (gridDim.x = nx*4)
  const int xcd = id & 7;
  const int rr = id >> 3;
  const int bx = xcd * nxq + (rr >> 2);
  const int by = rr & 3;

  const int tid = threadIdx.x;
  const int lane = tid & 63;
  const int w = tid >> 6;   // 0..7
  const int wc = w >> 2;    // code half (0..1)
  const int wm = w & 3;     // m quarter (0..3)
  const int row_base = bx * 256;
  const int code_base = by * 256;
  if (tid < 256) csq_s[tid] = csq[code_base + tid];

  const f32x4 zero = {0.f, 0.f, 0.f, 0.f};
  f32x4 acc[8][4];
#pragma unroll
  for (int fc = 0; fc < 8; ++fc)
#pragma unroll
    for (int fm = 0; fm < 4; ++fm) acc[fc][fm] = zero;

  const size_t aBase = ((size_t)(bx * 2) * 8) << 14;
  const size_t bBase = ((size_t)(by * 2) * 8) << 14;

  auto stage = [&](int buf, int kc) {
    char* dst = smem + buf * 65536;
    const char* gA0 = a_pack + aBase + ((size_t)kc << 14);
    const char* gA1 = a_pack + aBase + ((size_t)(8 + kc) << 14);
    const char* gB0 = cb_pack + bBase + ((size_t)kc << 14);
    const char* gB1 = cb_pack + bBase + ((size_t)(8 + kc) << 14);
    const int o = tid * 16;
#pragma unroll
    for (int p = 0; p < 2; ++p) {
      const int q = o + p * 8192;
      __builtin_amdgcn_global_load_lds(
          (const __attribute__((address_space(1))) u32*)(gA0 + q),
          (__attribute__((address_space(3))) u32*)(dst + q), 16, 0, 0);
      __builtin_amdgcn_global_load_lds(
          (const __attribute__((address_space(1))) u32*)(gA1 + q),
          (__attribute__((address_space(3))) u32*)(dst + 16384 + q), 16, 0, 0);
      __builtin_amdgcn_global_load_lds(
          (const __attribute__((address_space(1))) u32*)(gB0 + q),
          (__attribute__((address_space(3))) u32*)(dst + 32768 + q), 16, 0, 0);
      __builtin_amdgcn_global_load_lds(
          (const __attribute__((address_space(1))) u32*)(gB1 + q),
          (__attribute__((address_space(3))) u32*)(dst + 49152 + q), 16, 0, 0);
    }
  };

  stage(0, 0);
  __syncthreads();

  int cur = 0;
  for (int kc = 0; kc < 8; ++kc) {
    if (kc < 7) stage(cur ^ 1, kc + 1);  // loads in flight across compute
    const char* X = smem + cur * 65536;  // x rows (m dimension)
    const char* C = X + 32768;           // codebook rows
#pragma unroll
    for (int ks = 0; ks < 2; ++ks) {
      const int kb = ks * 64 + (lane >> 4) * 16;
      s16x8 af[8], bq[4];
#pragma unroll
      for (int fc = 0; fc < 8; ++fc) {
        const int cr = wc * 128 + fc * 16 + (lane & 15);
        af[fc] = *(const s16x8*)(C + ((cr >> 7) << 14) +
                                 tile_addr(cr & 127, kb));
      }
#pragma unroll
      for (int fm = 0; fm < 4; ++fm) {
        const int mr = wm * 64 + fm * 16 + (lane & 15);
        bq[fm] = *(const s16x8*)(X + ((mr >> 7) << 14) +
                                 tile_addr(mr & 127, kb));
      }
      __builtin_amdgcn_s_setprio(1);
#pragma unroll
      for (int fc = 0; fc < 8; ++fc)
#pragma unroll
        for (int fm = 0; fm < 4; ++fm)
          acc[fc][fm] = __builtin_amdgcn_mfma_f32_16x16x32_bf16(
              af[fc], bq[fm], acc[fc][fm], 0, 0, 0);
      __builtin_amdgcn_s_setprio(0);
    }
    __syncthreads();  // drains stage loads + all waves' LDS reads
    cur ^= 1;
  }

  u64 best[4] = {~0ull, ~0ull, ~0ull, ~0ull};
#pragma unroll
  for (int fc = 0; fc < 8; ++fc) {
#pragma unroll
    for (int r4 = 0; r4 < 4; ++r4) {
      const int cl = wc * 128 + fc * 16 + (lane >> 4) * 4 + r4;
      const float cs = csq_s[cl];
      const u64 codebits = (u32)(code_base + cl);
#pragma unroll
      for (int fm = 0; fm < 4; ++fm) {
        float d = fmaf(-2.0f, acc[fc][fm][r4], cs);
        u32 u = __float_as_uint(d);
        u = (u & 0x80000000u) ? ~u : (u | 0x80000000u);
        best[fm] = umin64(best[fm], ((u64)u << 32) | codebits);
      }
    }
  }
#pragma unroll
  for (int fm = 0; fm < 4; ++fm) {
    u64 b = best[fm];
#pragma unroll
    for (int off = 16; off < 64; off <<= 1) {
      u32 lo = (u32)b, hi = (u32)(b >> 32);
      lo = (u32)__shfl_xor((int)lo, off, 64);
      hi = (u32)__shfl_xor((int)hi, off, 64);
      b = umin64(b, ((u64)hi << 32) | lo);
    }
    if ((lane >> 4) == 0)
      atomicMin(&packed[row_base + wm * 64 + fm * 16 + (lane & 15)], b);
  }
}

// ---------------------------------------------------------------------------
// pack2: A2 = pool2(x - up1) + poolr2 f32 ([n][tau][c] layout).
__global__ __launch_bounds__(256) void pack2_kernel(
    const float* __restrict__ x, const float* __restrict__ cb,
    const u64* __restrict__ packed, char* __restrict__ a2,
    float* __restrict__ poolr2) {
  __shared__ float rows1[16][516];
  __shared__ int idx1[16];
  const int tid = threadIdx.x;
  const int blk = blockIdx.x;  // 16 n x 128 tiles
  const int n = blk >> 7;
  const int tau0 = (blk & 127) * 8;
  const int tb = tau0 * 2;  // full-res t in [tb, tb+16)
  if (tid < 16)
    idx1[tid] = (int)(packed[(size_t)n * TDIM + tb + tid] & 0xffffffffull);
  __syncthreads();
  {
    const int rj = tid >> 4, c16 = tid & 15;
    const float* src = cb + (size_t)idx1[rj] * CDIM;
#pragma unroll
    for (int q = 0; q < 8; ++q) {
      const int c = c16 * 4 + q * 64;
      *(f32x4*)&rows1[rj][c] = *(const f32x4*)(src + c);
    }
  }
  __syncthreads();

  const int cg = tid >> 1, half = tid & 1;
  const int c0 = cg * 4;
  const int tl0 = half * 8;  // local t base
  const size_t xbase =
      (size_t)n * (CDIM * TDIM) + (size_t)c0 * TDIM + tb + tl0;

  f32x4 ru[8];
#pragma unroll
  for (int t = 0; t < 8; ++t) ru[t] = *(const f32x4*)&rows1[tl0 + t][c0];

  float p2[4][4];  // [c][q]
#pragma unroll
  for (int j = 0; j < 4; ++j) {
    f32x4 xa = *(const f32x4*)(x + xbase + (size_t)j * TDIM);
    f32x4 xb = *(const f32x4*)(x + xbase + (size_t)j * TDIM + 4);
#pragma unroll
    for (int q = 0; q < 4; ++q) {
      const float e0 = (q < 2) ? xa[2 * q] : xb[2 * q - 4];
      const float e1 = (q < 2) ? xa[2 * q + 1] : xb[2 * q - 3];
      const float r0 = e0 - ru[2 * q][j];
      const float r1 = e1 - ru[2 * q + 1][j];
      p2[j][q] = (r0 + r1) * 0.5f;
    }
  }
  // poolr2 [n][tau][c]
#pragma unroll
  for (int q = 0; q < 4; ++q) {
    f32x4 o = {p2[0][q], p2[1][q], p2[2][q], p2[3][q]};
    *(f32x4*)(poolr2 + (size_t)n * (1024 * CDIM) +
              (size_t)(tau0 + half * 4 + q) * CDIM + c0) = o;
  }
  // a2 pack
  const int kc = c0 >> 6, kbyte = (c0 & 63) * 2;
#pragma unroll
  for (int q = 0; q < 4; ++q) {
    const int m = n * 1024 + tau0 + half * 4 + q;
    i32x2 o = {(int)pack2ch(p2[0][q], p2[1][q]),
               (int)pack2ch(p2[2][q], p2[3][q])};
    *(i32x2*)(a2 + (((size_t)((m >> 7) * 8 + kc)) << 14) +
              tile_addr(m & 127, kbyte)) = o;
  }
}

// ---------------------------------------------------------------------------
// packN: pool chain at coarse res; pin/pout layout [n][tau][c].
template <int TP, bool WPOOL>
__global__ __launch_bounds__(256) void packN_kernel(
    const float* __restrict__ pin, const float* __restrict__ cb,
    const u64* __restrict__ packed, char* __restrict__ a_next,
    float* __restrict__ pout) {
  constexpr int OFF = (TP == 1024) ? 32768 : 49152;  // scale-2 / scale-4 idx
  constexpr int TILES = TP / 16;
  constexpr int TO = TP / 2;
  __shared__ float rows[18][516];
  __shared__ int idxs[18];
  const int tid = threadIdx.x;
  const int blk = blockIdx.x;  // 16 n x TILES
  const int n = blk / TILES;
  const int o0 = (blk % TILES) * 8;  // output tau base
  const int s0 = o0 * 2;             // input sigma base
  if (tid < 18) {
    const int sig = iclamp(s0 - 1 + tid, 0, TP - 1);
    idxs[tid] = (int)(packed[OFF + (size_t)n * TP + sig] & 0xffffffffull);
  }
  __syncthreads();
  for (int j = 0; j < 18; ++j) {
    const int c = tid * 2;
    const float* src = cb + (size_t)idxs[j] * CDIM + c;
    rows[j][c] = src[0];
    rows[j][c + 1] = src[1];
  }
  __syncthreads();

  const int cg = tid >> 1, half = tid & 1;
  const int c0 = cg * 4;
  f32x4 inv[8];
#pragma unroll
  for (int l = 0; l < 8; ++l)
    inv[l] = *(const f32x4*)(pin + (size_t)n * (TP * CDIM) +
                             (size_t)(s0 + half * 8 + l) * CDIM + c0);

  float pv[4][4];
#pragma unroll
  for (int q = 0; q < 4; ++q) {
    const int e = half * 8 + 2 * q;
    const int sa = e + 1, sb = e + 2;
    f32x4 Rm = *(const f32x4*)&rows[sa - 1][c0];
    f32x4 Rc = *(const f32x4*)&rows[sa][c0];
    f32x4 Rp = *(const f32x4*)&rows[sb][c0];
    f32x4 Rpp = *(const f32x4*)&rows[sb + 1][c0];
    f32x4 ua = 0.125f * (Rm + Rp) + 0.75f * Rc;
    f32x4 ub = 0.125f * (Rc + Rpp) + 0.75f * Rp;
#pragma unroll
    for (int j = 0; j < 4; ++j)
      pv[j][q] = ((inv[2 * q][j] - ua[j]) + (inv[2 * q + 1][j] - ub[j])) * 0.5f;
  }

  if constexpr (WPOOL) {
#pragma unroll
    for (int q = 0; q < 4; ++q) {
      f32x4 o = {pv[0][q], pv[1][q], pv[2][q], pv[3][q]};
      *(f32x4*)(pout + (size_t)n * (TO * CDIM) +
                (size_t)(o0 + half * 4 + q) * CDIM + c0) = o;
    }
  }
  const int kc = c0 >> 6, kbyte = (c0 & 63) * 2;
#pragma unroll
  for (int q = 0; q < 4; ++q) {
    const int m = n * TO + o0 + half * 4 + q;
    i32x2 o = {(int)pack2ch(pv[0][q], pv[1][q]),
               (int)pack2ch(pv[2][q], pv[3][q])};
    *(i32x2*)(a_next + (((size_t)((m >> 7) * 8 + kc)) << 14) +
              tile_addr(m & 127, kbyte)) = o;
  }
}

// ---------------------------------------------------------------------------
// final: one full-res pass: 4 per-stage losses + f_hat.
__global__ __launch_bounds__(256) void final_kernel(
    const float* __restrict__ x, float* __restrict__ out,
    const float* __restrict__ cb, const u64* __restrict__ packed,
    float* __restrict__ lossPart) {
  __shared__ float rows1[16][516];
  __shared__ int idx1[16];
  __shared__ float red[4][4];
  const int tid = threadIdx.x;
  const int blk = blockIdx.x;  // 16 n x 128 tiles
  const int n = blk >> 7;
  const int t0 = (blk & 127) * 16;
  if (tid < 16)
    idx1[tid] = (int)(packed[(size_t)n * TDIM + t0 + tid] & 0xffffffffull);
  __syncthreads();
  {
    const int rj = tid >> 4, c16 = tid & 15;
    const float* src = cb + (size_t)idx1[rj] * CDIM;
#pragma unroll
    for (int q = 0; q < 8; ++q) {
      const int c = c16 * 4 + q * 64;
      *(f32x4*)&rows1[rj][c] = *(const f32x4*)(src + c);
    }
  }
  __syncthreads();

  const int cg = tid >> 1, half = tid & 1;
  const int c0 = cg * 4;
  const int tb = t0 + half * 8;
  const int b2 = tb >> 1, b4 = tb >> 2, m8 = tb >> 3;
  const u64* ip2 = packed + 32768 + (size_t)n * 1024;
  const u64* ip4 = packed + 49152 + (size_t)n * 512;
  const u64* ip8 = packed + 57344 + (size_t)n * 256;

  f32x4 R2[6], R4[4], R8[3];
#pragma unroll
  for (int k = 0; k < 6; ++k) {
    const int s = iclamp(b2 - 1 + k, 0, 1023);
    R2[k] = *(const f32x4*)(
        cb + (size_t)(u32)(ip2[s] & 0xffffffffull) * CDIM + c0);
  }
#pragma unroll
  for (int k = 0; k < 4; ++k) {
    const int s = iclamp(b4 - 1 + k, 0, 511);
    R4[k] = *(const f32x4*)(
        cb + (size_t)(u32)(ip4[s] & 0xffffffffull) * CDIM + c0);
  }
#pragma unroll
  for (int k = 0; k < 3; ++k) {
    const int s = iclamp(m8 - 1 + k, 0, 255);
    R8[k] = *(const f32x4*)(
        cb + (size_t)(u32)(ip8[s] & 0xffffffffull) * CDIM + c0);
  }

  const size_t xbase = (size_t)n * (CDIM * TDIM) + (size_t)c0 * TDIM + tb;
  f32x4 xa[4], xb[4], fa[4], fb[4];
#pragma unroll
  for (int j = 0; j < 4; ++j) {
    xa[j] = *(const f32x4*)(x + xbase + (size_t)j * TDIM);
    xb[j] = *(const f32x4*)(x + xbase + (size_t)j * TDIM + 4);
  }

  const int s2s[8] = {0, 1, 1, 2, 2, 3, 3, 4};
  const float w2s[8] = {0.75f, 0.25f, 0.75f, 0.25f, 0.75f, 0.25f, 0.75f, 0.25f};
  const int s4s[8] = {0, 0, 1, 1, 1, 1, 2, 2};
  const float w4s[8] = {0.625f, 0.875f, 0.125f, 0.375f,
                        0.625f, 0.875f, 0.125f, 0.375f};
  const int s8s[8] = {0, 0, 0, 0, 1, 1, 1, 1};
  const float w8s[8] = {0.5625f, 0.6875f, 0.8125f, 0.9375f,
                        0.0625f, 0.1875f, 0.3125f, 0.4375f};

  float ss1 = 0.f, ss2 = 0.f, ss3 = 0.f, ss4 = 0.f;
#pragma unroll
  for (int tt = 0; tt < 8; ++tt) {
    f32x4 ru1 = *(const f32x4*)&rows1[half * 8 + tt][c0];
    f32x4 u2 = R2[s2s[tt]] * (1.f - w2s[tt]) + R2[s2s[tt] + 1] * w2s[tt];
    f32x4 u4 = R4[s4s[tt]] * (1.f - w4s[tt]) + R4[s4s[tt] + 1] * w4s[tt];
    f32x4 u8 = R8[s8s[tt]] * (1.f - w8s[tt]) + R8[s8s[tt] + 1] * w8s[tt];
    f32x4 xv;
#pragma unroll
    for (int j = 0; j < 4; ++j) xv[j] = (tt < 4) ? xa[j][tt] : xb[j][tt - 4];
    f32x4 r1 = xv - ru1;
    f32x4 r2 = r1 - u2;
    f32x4 r3 = r2 - u4;
    f32x4 r4 = r3 - u8;
#pragma unroll
    for (int j = 0; j < 4; ++j) {
      ss1 += r1[j] * r1[j];
      ss2 += r2[j] * r2[j];
      ss3 += r3[j] * r3[j];
      ss4 += r4[j] * r4[j];
    }
    f32x4 fh = xv - r4;
#pragma unroll
    for (int j = 0; j < 4; ++j) {
      if (tt < 4)
        fa[j][tt] = fh[j];
      else
        fb[j][tt - 4] = fh[j];
    }
  }
#pragma unroll
  for (int j = 0; j < 4; ++j) {
    *(f32x4*)(out + xbase + (size_t)j * TDIM) = fa[j];
    *(f32x4*)(out + xbase + (size_t)j * TDIM + 4) = fb[j];
  }

  float sv[4] = {ss1, ss2, ss3, ss4};
  const int w = tid >> 6, lane = tid & 63;
#pragma unroll
  for (int st = 0; st < 4; ++st) {
    float v = sv[st];
#pragma unroll
    for (int off = 32; off; off >>= 1) v += __shfl_down(v, off, 64);
    if (lane == 0) red[w][st] = v;
  }
  __syncthreads();
  if (tid < 4)
    lossPart[tid * 2048 + blk] =
        red[0][tid] + red[1][tid] + red[2][tid] + red[3][tid];
}

// ---------------------------------------------------------------------------
__global__ __launch_bounds__(256) void hist_kernel(const u64* __restrict__ packed,
                                                   int* __restrict__ hist) {
  const int i = blockIdx.x * 256 + threadIdx.x;  // 61440 total
  const int code = (int)(packed[i] & 0xFFFFFFFFull);
  atomicAdd(&hist[code], 1);
}

__global__ __launch_bounds__(256) void finalize_kernel(
    const float* __restrict__ lossPart, const int* __restrict__ hist,
    float* __restrict__ outTail) {
  __shared__ float red[4];
  const int tid = threadIdx.x;
  float s = 0.f;
  for (int i = tid; i < 4 * 2048; i += 256) s += lossPart[i];
#pragma unroll
  for (int off = 32; off; off >>= 1) s += __shfl_down(s, off, 64);
  if ((tid & 63) == 0) red[tid >> 6] = s;
  __syncthreads();
  const float loss =
      (red[0] + red[1] + red[2] + red[3]) * (1.0f / (4.0f * 16777216.0f));
  __syncthreads();
  float e = 0.f;
  for (int k = tid; k < KCODE; k += 256) {
    float p = (float)hist[k] * (1.0f / 61440.0f);
    e += p * logf(p + 1e-7f);
  }
#pragma unroll
  for (int off = 32; off; off >>= 1) e += __shfl_down(e, off, 64);
  if ((tid & 63) == 0) red[tid >> 6] = e;
  __syncthreads();
  if (tid == 0) {
    outTail[0] = loss;
    outTail[1] = expf(-(red[0] + red[1] + red[2] + red[3]));
  }
}

// ---------------------------------------------------------------------------
extern "C" void kernel_launch(void* const* d_in, const int* in_sizes, int n_in,
                              void* d_out, int out_size, void* d_ws,
                              size_t ws_size, hipStream_t stream) {
  const float* x = (const float*)d_in[0];
  const float* cb = (const float*)d_in[1];
  float* out = (float*)d_out;

  char* ws = (char*)d_ws;
  u64* packed = (u64*)ws;                   // 491520 B
  float* csq = (float*)(ws + 491520);       // 4096 B
  int* hist = (int*)(ws + 495616);          // 4096 B
  float* lossPart = (float*)(ws + 499712);  // 32768 B (4 x 2048)
  char* cb_pack = ws + 565248;              // 1 MiB
  char* a2 = ws + (2ull << 20);             // 16 MiB
  char* a4 = ws + (18ull << 20);            // 8 MiB
  char* a8 = ws + (26ull << 20);            // 4 MiB

  hipMemsetAsync(packed, 0xFF, (size_t)M_TOTAL * 8, stream);
  hipMemsetAsync(hist, 0, KCODE * sizeof(int), stream);
  csq_kernel<<<KCODE, 64, 0, stream>>>(cb, csq);
  cbprep_kernel<<<256, 256, 0, stream>>>(cb, cb_pack);

  u64* p1 = packed;          // 32768 rows (t_s=2048)
  u64* p2 = packed + 32768;  // 16384 rows
  u64* p4 = packed + 49152;  //  8192 rows
  u64* p8 = packed + 57344;  //  4096 rows

  // d_out region reuse: A1 (32MB) until gemm1; then poolr2 [0,32MB) +
  // poolr4 [32,48MB); finally f_hat overwrites everything.
  char* a1 = (char*)out;
  float* poolr2 = out;            // [n][1024][512] f32 = 32 MB
  float* poolr4 = out + 8388608;  // [n][512][512]  f32 = 16 MB

  xprep_kernel<<<1024, 256, 0, stream>>>(x, a1);
  gemm_argmin_packed<<<128 * 4, 512, 0, stream>>>(a1, cb_pack, csq, p1);
  pack2_kernel<<<2048, 256, 0, stream>>>(x, cb, packed, a2, poolr2);
  gemm_argmin_packed<<<64 * 4, 512, 0, stream>>>(a2, cb_pack, csq, p2);
  packN_kernel<1024, true>
      <<<1024, 256, 0, stream>>>(poolr2, cb, packed, a4, poolr4);
  gemm_argmin_packed<<<32 * 4, 512, 0, stream>>>(a4, cb_pack, csq, p4);
  packN_kernel<512, false>
      <<<512, 256, 0, stream>>>(poolr4, cb, packed, a8, nullptr);
  gemm_argmin_packed<<<16 * 4, 512, 0, stream>>>(a8, cb_pack, csq, p8);
  final_kernel<<<2048, 256, 0, stream>>>(x, out, cb, packed, lossPart);

  hist_kernel<<<240, 256, 0, stream>>>(packed, hist);
  finalize_kernel<<<1, 256, 0, stream>>>(lossPart, hist, out + FH_ELEMS);
}